// Round 8
// baseline (248.759 us; speedup 1.0000x reference)
//
#include <hip/hip_runtime.h>
#include <cstdint>
#include <cstddef>

// Problem dims (compile-time)
#define B_DIM 2
#define L_DIM 2048
#define E_DIM 1024
#define H_DIM 16
#define HD    64
#define M_ROWS (B_DIM * L_DIM)   // 4096
#define QKV_N  (3 * E_DIM)       // 3072
#define C_CONST 2.01f

typedef unsigned short ushort_t;
typedef __attribute__((ext_vector_type(8))) short bf16x8;
typedef __attribute__((ext_vector_type(4))) float f32x4;

__device__ __forceinline__ unsigned int f2bf(float f) {
    union { float f; unsigned int u; } v; v.f = f;
    return (v.u + 0x7FFFu + ((v.u >> 16) & 1u)) >> 16;   // RNE
}

__device__ __forceinline__ void gload16(const void* g, void* l) {
    __builtin_amdgcn_global_load_lds(
        (const __attribute__((address_space(1))) void*)g,
        (__attribute__((address_space(3))) void*)l, 16, 0, 0);
}

// ---------------------------------------------------------------------------
// cast fp32 -> bf16 (contiguous), 4 elems/thread
// ---------------------------------------------------------------------------
__global__ __launch_bounds__(256) void cast_bf16_kernel(
    const float* __restrict__ in, ushort_t* __restrict__ out, int n4)
{
    const int i = blockIdx.x * 256 + threadIdx.x;
    if (i >= n4) return;
    const float4 v = ((const float4*)in)[i];
    uint2 p;
    p.x = f2bf(v.x) | (f2bf(v.y) << 16);
    p.y = f2bf(v.z) | (f2bf(v.w) << 16);
    ((uint2*)out)[i] = p;
}

// ---------------------------------------------------------------------------
// transpose fp32 [R][Cn] -> bf16 [Cn][R]
// ---------------------------------------------------------------------------
__global__ __launch_bounds__(256) void transpose_bf16_kernel(
    const float* __restrict__ in, ushort_t* __restrict__ out, int R, int Cn)
{
    __shared__ float t[64][65];
    const int c0 = blockIdx.x * 64, r0 = blockIdx.y * 64;
    const int tid = threadIdx.x;
    for (int idx = tid; idx < 4096; idx += 256) {
        const int r = idx >> 6, c = idx & 63;
        t[r][c] = in[(size_t)(r0 + r) * Cn + c0 + c];
    }
    __syncthreads();
    for (int idx = tid; idx < 4096; idx += 256) {
        const int c = idx >> 6, r = idx & 63;
        out[(size_t)(c0 + c) * R + r0 + r] = (ushort_t)f2bf(t[r][c]);
    }
}

// ---------------------------------------------------------------------------
// gather ctx [bh][l][d] fp32 -> cb [m=b*2048+l][e=h*64+d] bf16
// ---------------------------------------------------------------------------
__global__ __launch_bounds__(256) void gather_ctx_kernel(
    const float* __restrict__ ctx, ushort_t* __restrict__ cb)
{
    const int gid = blockIdx.x * 256 + threadIdx.x;
    const int m = gid >> 8, e4 = gid & 255;
    const int b = m >> 11, l = m & 2047;
    const int h = e4 >> 4, d = (e4 & 15) * 4;
    const float4 v = *(const float4*)&ctx[(((size_t)(b * H_DIM + h) * L_DIM + l) * HD + d)];
    uint2 p;
    p.x = f2bf(v.x) | (f2bf(v.y) << 16);
    p.y = f2bf(v.z) | (f2bf(v.w) << 16);
    ((uint2*)cb)[gid] = p;
}

// ---------------------------------------------------------------------------
// bf16 MFMA GEMM, 128x128 tile, BK=32, 4 waves. MODE 0: scatter q,k fp32 and
// v bf16 into [B,H,L,D] bufs. MODE 1: plain C+bias fp32.
// ---------------------------------------------------------------------------
template<int NCOLS, int MODE>
__global__ __launch_bounds__(256) void gemm_bt_kernel(
    const ushort_t* __restrict__ A, const ushort_t* __restrict__ BT,
    const float* __restrict__ bias,
    float* __restrict__ d0, float* __restrict__ d1, ushort_t* __restrict__ d2)
{
    __shared__ __align__(16) ushort_t Abuf[128 * 32];
    __shared__ __align__(16) ushort_t Bbuf[128 * 32];
    const int tid = threadIdx.x;
    const int wave = tid >> 6, lane = tid & 63;
    const int m0 = blockIdx.x * 128, n0 = blockIdx.y * 128;
    const int wr = (wave >> 1) * 64, wc = (wave & 1) * 64;
    const int g = lane >> 4, l15 = lane & 15;

    f32x4 acc[4][4];
    #pragma unroll
    for (int i = 0; i < 4; ++i)
        #pragma unroll
        for (int j = 0; j < 4; ++j) acc[i][j] = f32x4{0.f, 0.f, 0.f, 0.f};

    const int sr = tid >> 2;
    const int sc = (tid & 3) * 8;
    const ushort_t* Asrc0 = A + (size_t)(m0 + sr) * 1024 + sc;
    const ushort_t* Asrc1 = A + (size_t)(m0 + 64 + sr) * 1024 + sc;
    const ushort_t* Bsrc0 = BT + (size_t)(n0 + sr) * 1024 + sc;
    const ushort_t* Bsrc1 = BT + (size_t)(n0 + 64 + sr) * 1024 + sc;
    ushort_t* Adst0 = &Abuf[tid * 8];
    ushort_t* Adst1 = &Abuf[2048 + tid * 8];
    ushort_t* Bdst0 = &Bbuf[tid * 8];
    ushort_t* Bdst1 = &Bbuf[2048 + tid * 8];

    for (int k0 = 0; k0 < 1024; k0 += 32) {
        __syncthreads();
        gload16(Asrc0 + k0, Adst0);
        gload16(Asrc1 + k0, Adst1);
        gload16(Bsrc0 + k0, Bdst0);
        gload16(Bsrc1 + k0, Bdst1);
        __syncthreads();

        bf16x8 af[4];
        #pragma unroll
        for (int mt = 0; mt < 4; ++mt)
            af[mt] = *(const bf16x8*)&Abuf[(wr + mt * 16 + l15) * 32 + 8 * g];
        #pragma unroll
        for (int nt = 0; nt < 4; ++nt) {
            const bf16x8 bfr = *(const bf16x8*)&Bbuf[(wc + nt * 16 + l15) * 32 + 8 * g];
            #pragma unroll
            for (int mt = 0; mt < 4; ++mt)
                acc[mt][nt] = __builtin_amdgcn_mfma_f32_16x16x32_bf16(af[mt], bfr, acc[mt][nt], 0, 0, 0);
        }
    }

    #pragma unroll
    for (int nt = 0; nt < 4; ++nt) {
        const int n = n0 + wc + nt * 16 + l15;
        const float bv = bias[n];
        if (MODE == 0) {
            const int sel = n >> 10, h = (n & 1023) >> 6, d = n & 63;
            #pragma unroll
            for (int mt = 0; mt < 4; ++mt) {
                #pragma unroll
                for (int r = 0; r < 4; ++r) {
                    const int m = m0 + wr + mt * 16 + 4 * g + r;
                    const int bb = m >> 11, ll = m & 2047;
                    const size_t idx = ((size_t)((bb * H_DIM + h) * L_DIM + ll)) * HD + d;
                    const float val = acc[mt][nt][r] + bv;
                    if (sel == 0)      d0[idx] = val;
                    else if (sel == 1) d1[idx] = val;
                    else               d2[idx] = (ushort_t)f2bf(val);
                }
            }
        } else {
            #pragma unroll
            for (int mt = 0; mt < 4; ++mt) {
                #pragma unroll
                for (int r = 0; r < 4; ++r) {
                    const int m = m0 + wr + mt * 16 + 4 * g + r;
                    d0[(size_t)m * E_DIM + n] = acc[mt][nt][r] + bv;
                }
            }
        }
    }
}

// ---------------------------------------------------------------------------
// L2-normalize rows of fp32 [nrows][64], write bf16.
// ---------------------------------------------------------------------------
__global__ __launch_bounds__(256) void normalize_bf16_kernel(
    const float* __restrict__ in, ushort_t* __restrict__ out)
{
    const int r = blockIdx.x * 4 + (threadIdx.x >> 6);
    const int lane = threadIdx.x & 63;
    float v = in[(size_t)r * HD + lane];
    float s = v * v;
    #pragma unroll
    for (int m = 1; m < 64; m <<= 1) s += __shfl_xor(s, m);
    out[(size_t)r * HD + lane] = (ushort_t)f2bf(v * (1.0f / sqrtf(s)));
}

// ---------------------------------------------------------------------------
// transpose vb16 [bh][key][64] -> vt16 [bh][d][2048]
// ---------------------------------------------------------------------------
__global__ __launch_bounds__(256) void vt_transpose_kernel(
    const ushort_t* __restrict__ vb, ushort_t* __restrict__ vt)
{
    __shared__ ushort_t t[64][68];
    const int kt = blockIdx.x, bh = blockIdx.y;
    const int tid = threadIdx.x;
    const ushort_t* src = vb + ((size_t)bh * L_DIM + kt * 64) * HD;
    #pragma unroll
    for (int p = 0; p < 16; ++p) {
        const int idx = tid + 256 * p;
        t[idx >> 6][idx & 63] = src[idx];
    }
    __syncthreads();
    ushort_t* dst = vt + (size_t)bh * HD * L_DIM + kt * 64;
    #pragma unroll
    for (int p = 0; p < 16; ++p) {
        const int idx = tid + 256 * p;
        const int d = idx >> 6, k = idx & 63;
        dst[(size_t)d * L_DIM + k] = t[k][d];
    }
}

// ---------------------------------------------------------------------------
// MFMA flash attention. Block = 64 q-rows, 4 waves x 16 rows, kv tiles of 64.
// qt reversed (heavy blocks dispatched first -> LPT schedule). Swapped QK^T,
// online softmax (lane-local rows), P packed-b64 to LDS, PV. All LDS tiles
// XOR-swizzled (16B chunk ^= row&7) with pre-swizzled global sources.
// ---------------------------------------------------------------------------
__global__ __launch_bounds__(256) void attn_mfma_kernel(
    const ushort_t* __restrict__ qn, const ushort_t* __restrict__ kn,
    const ushort_t* __restrict__ vt, float* __restrict__ ctx)
{
    __shared__ __align__(16) ushort_t Qs[64 * 64];
    __shared__ __align__(16) ushort_t Ks[64 * 64];
    __shared__ __align__(16) ushort_t Vs[64 * 64];
    __shared__ __align__(16) ushort_t Ps[4][16 * 64];

    const int qt = (L_DIM / 64 - 1) - blockIdx.x;   // 31..0, heavy first
    const int bh = blockIdx.y;
    const int q0 = qt * 64;
    const int tid = threadIdx.x, w = tid >> 6, lane = tid & 63;
    const int g = lane >> 4, l15 = lane & 15;
    ushort_t* Pw = &Ps[w][0];

    const ushort_t* Qg = qn + ((size_t)bh * L_DIM + q0) * HD;
    const ushort_t* Kg = kn + (size_t)bh * L_DIM * HD;
    const ushort_t* Vg = vt + (size_t)bh * HD * L_DIM;

    // stage Q (512 x 16B chunks), source pre-swizzled
    #pragma unroll
    for (int p = 0; p < 2; ++p) {
        const int c = tid + 256 * p;
        const int row = c >> 3, ch = c & 7;
        gload16(Qg + row * 64 + ((ch ^ (row & 7)) << 3), Qs + row * 64 + (ch << 3));
    }
    __syncthreads();

    // Q fragments (constant over key loop); wave w owns rows 16w..16w+15
    bf16x8 qf[2];
    #pragma unroll
    for (int kc = 0; kc < 2; ++kc) {
        const int row = 16 * w + l15;
        qf[kc] = *(const bf16x8*)&Qs[row * 64 + (((4 * kc + g) ^ (row & 7)) << 3)];
    }

    f32x4 o[4];
    float m_i = 0.f, l_i = 0.f;   // scores >= 0, so m init 0 is safe
    #pragma unroll
    for (int j = 0; j < 4; ++j) o[j] = f32x4{0.f, 0.f, 0.f, 0.f};

    const int nkt = qt + 1;
    for (int kt = 0; kt < nkt; ++kt) {
        const int j0 = kt * 64;
        __syncthreads();   // all waves done reading Ks/Vs of prior tile
        #pragma unroll
        for (int p = 0; p < 2; ++p) {
            const int c = tid + 256 * p;
            const int row = c >> 3, ch = c & 7;
            gload16(Kg + (size_t)(j0 + row) * 64 + ((ch ^ (row & 7)) << 3),
                    Ks + row * 64 + (ch << 3));
            gload16(Vg + (size_t)row * L_DIM + j0 + ((ch ^ (row & 7)) << 3),
                    Vs + row * 64 + (ch << 3));
        }
        __syncthreads();   // staged tiles visible

        // ---- S^T = K . Q^T  (keys along D-rows, q-rows along D-cols) ----
        bf16x8 ak[4][2];
        #pragma unroll
        for (int kt4 = 0; kt4 < 4; ++kt4)
            #pragma unroll
            for (int kc = 0; kc < 2; ++kc) {
                const int row = 16 * kt4 + l15;
                ak[kt4][kc] = *(const bf16x8*)&Ks[row * 64 + (((4 * kc + g) ^ (row & 7)) << 3)];
            }
        f32x4 st[4];
        #pragma unroll
        for (int kt4 = 0; kt4 < 4; ++kt4) st[kt4] = f32x4{0.f, 0.f, 0.f, 0.f};
        #pragma unroll
        for (int kc = 0; kc < 2; ++kc)
            #pragma unroll
            for (int kt4 = 0; kt4 < 4; ++kt4)
                st[kt4] = __builtin_amdgcn_mfma_f32_16x16x32_bf16(
                    ak[kt4][kc], qf[kc], st[kt4], 0, 0, 0);

        // ---- score transform + mask + online softmax (q-row = l15, lane-local) ----
        const int qrow = q0 + 16 * w + l15;
        float mx = 0.0f;
        #pragma unroll
        for (int kt4 = 0; kt4 < 4; ++kt4)
            #pragma unroll
            for (int r = 0; r < 4; ++r) {
                const int key = j0 + 16 * kt4 + 4 * g + r;
                const float x = st[kt4][r];
                float sc = __fdividef(x * x, C_CONST - 2.f * x);
                sc = (key > qrow) ? -1e30f : sc;
                st[kt4][r] = sc;
                mx = fmaxf(mx, sc);
            }
        mx = fmaxf(mx, __shfl_xor(mx, 16));
        mx = fmaxf(mx, __shfl_xor(mx, 32));
        const float newm = fmaxf(m_i, mx);
        const float scl = __expf(m_i - newm);
        m_i = newm;
        float ts = 0.f;
        #pragma unroll
        for (int kt4 = 0; kt4 < 4; ++kt4)
            #pragma unroll
            for (int r = 0; r < 4; ++r) {
                const float pv = __expf(st[kt4][r] - newm);
                st[kt4][r] = pv;
                ts += pv;
            }
        ts += __shfl_xor(ts, 16);
        ts += __shfl_xor(ts, 32);
        l_i = l_i * scl + ts;

        // ---- pack P -> LDS (b64, 4 consecutive keys per lane) ----
        {
            const int qr = l15;
            #pragma unroll
            for (int kt4 = 0; kt4 < 4; ++kt4) {
                const int ch = 2 * kt4 + (g >> 1);
                uint2 pk;
                pk.x = f2bf(st[kt4][0]) | (f2bf(st[kt4][1]) << 16);
                pk.y = f2bf(st[kt4][2]) | (f2bf(st[kt4][3]) << 16);
                *(uint2*)&Pw[qr * 64 + ((ch ^ (qr & 7)) << 3) + 4 * (g & 1)] = pk;
            }
        }

        // ---- rescale O (acc row = 4g+r lives in lane group; scl is at lane l15=row) ----
        #pragma unroll
        for (int r = 0; r < 4; ++r) {
            const float s = __shfl(scl, 4 * g + r);
            #pragma unroll
            for (int dt = 0; dt < 4; ++dt) o[dt][r] *= s;
        }

        // ---- O += P . V ----
        bf16x8 ap[2], av[4][2];
        #pragma unroll
        for (int kc = 0; kc < 2; ++kc) {
            const int row = l15;
            ap[kc] = *(const bf16x8*)&Pw[row * 64 + (((4 * kc + g) ^ (row & 7)) << 3)];
        }
        #pragma unroll
        for (int dt = 0; dt < 4; ++dt)
            #pragma unroll
            for (int kc = 0; kc < 2; ++kc) {
                const int row = 16 * dt + l15;
                av[dt][kc] = *(const bf16x8*)&Vs[row * 64 + (((4 * kc + g) ^ (row & 7)) << 3)];
            }
        #pragma unroll
        for (int kc = 0; kc < 2; ++kc)
            #pragma unroll
            for (int dt = 0; dt < 4; ++dt)
                o[dt] = __builtin_amdgcn_mfma_f32_16x16x32_bf16(
                    ap[kc], av[dt][kc], o[dt], 0, 0, 0);
    }

    // ---- epilogue: divide by l, store fp32 ctx ----
    float* Og = ctx + ((size_t)bh * L_DIM + q0 + 16 * w) * HD;
    #pragma unroll
    for (int r = 0; r < 4; ++r) {
        const float lv = __shfl(l_i, 4 * g + r);
        const float inv = 1.0f / lv;
        #pragma unroll
        for (int dt = 0; dt < 4; ++dt)
            Og[(size_t)(4 * g + r) * HD + 16 * dt + l15] = o[dt][r] * inv;
    }
}

// ---------------------------------------------------------------------------
extern "C" void kernel_launch(void* const* d_in, const int* in_sizes, int n_in,
                              void* d_out, int out_size, void* d_ws, size_t ws_size,
                              hipStream_t stream)
{
    const float* x    = (const float*)d_in[0];
    const float* Wqkv = (const float*)d_in[1];
    const float* bqkv = (const float*)d_in[2];
    const float* Wout = (const float*)d_in[3];
    const float* bout = (const float*)d_in[4];
    float* out = (float*)d_out;

    char* ws = (char*)d_ws;
    const size_t MB = 1u << 20;
    float*    qb    = (float*)   (ws + 0 * MB);    // [0,16) fp32 q
    float*    kb    = (float*)   (ws + 16 * MB);   // [16,32) fp32 k
    ushort_t* vb16  = (ushort_t*)(ws + 32 * MB);   // [32,40) bf16 v
    ushort_t* xb    = (ushort_t*)(ws + 40 * MB);   // [40,48) bf16 x     (dead after qkv gemm)
    ushort_t* WqkvT = (ushort_t*)(ws + 48 * MB);   // [48,54)            (dead after qkv gemm)
    ushort_t* kn16  = (ushort_t*)(ws + 40 * MB);   // reuse xb slot
    ushort_t* qn16  = (ushort_t*)(ws + 48 * MB);   // reuse WqkvT slot
    ushort_t* vt16  = (ushort_t*)(ws + 56 * MB);   // [56,64)
    float*    ctx   = (float*)   (ws + 0 * MB);    // reuse qb slot (qb dead after normalize)
    ushort_t* cb    = (ushort_t*)(ws + 16 * MB);   // reuse kb slot
    ushort_t* WoutT = (ushort_t*)(ws + 24 * MB);   // [24,26)

    // 1) bf16 copies for the qkv GEMM
    cast_bf16_kernel<<<4096, 256, 0, stream>>>(x, xb, (M_ROWS * E_DIM) / 4);
    transpose_bf16_kernel<<<dim3(QKV_N / 64, E_DIM / 64), 256, 0, stream>>>(Wqkv, WqkvT, E_DIM, QKV_N);

    // 2) qkv GEMM: q,k fp32; v bf16
    gemm_bt_kernel<QKV_N, 0><<<dim3(M_ROWS / 128, QKV_N / 128), 256, 0, stream>>>(
        xb, WqkvT, bqkv, qb, kb, vb16);

    // 3) normalize q,k -> bf16
    const int nrows = B_DIM * H_DIM * L_DIM;  // 65536
    normalize_bf16_kernel<<<nrows / 4, 256, 0, stream>>>(qb, qn16);
    normalize_bf16_kernel<<<nrows / 4, 256, 0, stream>>>(kb, kn16);

    // 4) transpose v -> vt16 [bh][d][key]
    vt_transpose_kernel<<<dim3(L_DIM / 64, B_DIM * H_DIM), 256, 0, stream>>>(vb16, vt16);

    // 5) MFMA flash attention (64-row q-tiles, heavy-first)
    attn_mfma_kernel<<<dim3(L_DIM / 64, B_DIM * H_DIM), 256, 0, stream>>>(qn16, kn16, vt16, ctx);

    // 6) gather ctx -> bf16 [M][E]; transpose W_out
    gather_ctx_kernel<<<4096, 256, 0, stream>>>(ctx, cb);
    transpose_bf16_kernel<<<dim3(E_DIM / 64, E_DIM / 64), 256, 0, stream>>>(Wout, WoutT, E_DIM, E_DIM);

    // 7) out = ctx @ W_out + b (MFMA)
    gemm_bt_kernel<E_DIM, 1><<<dim3(M_ROWS / 128, E_DIM / 128), 256, 0, stream>>>(
        cb, WoutT, bout, out, nullptr, nullptr);
}

// Round 9
// 225.152 us; speedup vs baseline: 1.1048x; 1.1048x over previous
//
#include <hip/hip_runtime.h>
#include <cstdint>
#include <cstddef>

// Problem dims (compile-time)
#define B_DIM 2
#define L_DIM 2048
#define E_DIM 1024
#define H_DIM 16
#define HD    64
#define M_ROWS (B_DIM * L_DIM)   // 4096
#define QKV_N  (3 * E_DIM)       // 3072
#define C_CONST 2.01f

typedef unsigned short ushort_t;
typedef __attribute__((ext_vector_type(8))) short bf16x8;
typedef __attribute__((ext_vector_type(4))) float f32x4;

__device__ __forceinline__ unsigned int f2bf(float f) {
    union { float f; unsigned int u; } v; v.f = f;
    return (v.u + 0x7FFFu + ((v.u >> 16) & 1u)) >> 16;   // RNE
}

__device__ __forceinline__ void gload16(const void* g, void* l) {
    __builtin_amdgcn_global_load_lds(
        (const __attribute__((address_space(1))) void*)g,
        (__attribute__((address_space(3))) void*)l, 16, 0, 0);
}

// ---------------------------------------------------------------------------
// cast fp32 -> bf16 (contiguous), 4 elems/thread
// ---------------------------------------------------------------------------
__global__ __launch_bounds__(256) void cast_bf16_kernel(
    const float* __restrict__ in, ushort_t* __restrict__ out, int n4)
{
    const int i = blockIdx.x * 256 + threadIdx.x;
    if (i >= n4) return;
    const float4 v = ((const float4*)in)[i];
    uint2 p;
    p.x = f2bf(v.x) | (f2bf(v.y) << 16);
    p.y = f2bf(v.z) | (f2bf(v.w) << 16);
    ((uint2*)out)[i] = p;
}

// ---------------------------------------------------------------------------
// transpose fp32 [R][Cn] -> bf16 [Cn][R]
// ---------------------------------------------------------------------------
__global__ __launch_bounds__(256) void transpose_bf16_kernel(
    const float* __restrict__ in, ushort_t* __restrict__ out, int R, int Cn)
{
    __shared__ float t[64][65];
    const int c0 = blockIdx.x * 64, r0 = blockIdx.y * 64;
    const int tid = threadIdx.x;
    for (int idx = tid; idx < 4096; idx += 256) {
        const int r = idx >> 6, c = idx & 63;
        t[r][c] = in[(size_t)(r0 + r) * Cn + c0 + c];
    }
    __syncthreads();
    for (int idx = tid; idx < 4096; idx += 256) {
        const int c = idx >> 6, r = idx & 63;
        out[(size_t)(c0 + c) * R + r0 + r] = (ushort_t)f2bf(t[r][c]);
    }
}

// ---------------------------------------------------------------------------
// gather ctx [bh][l][d] fp32 -> cb [m=b*2048+l][e=h*64+d] bf16
// ---------------------------------------------------------------------------
__global__ __launch_bounds__(256) void gather_ctx_kernel(
    const float* __restrict__ ctx, ushort_t* __restrict__ cb)
{
    const int gid = blockIdx.x * 256 + threadIdx.x;
    const int m = gid >> 8, e4 = gid & 255;
    const int b = m >> 11, l = m & 2047;
    const int h = e4 >> 4, d = (e4 & 15) * 4;
    const float4 v = *(const float4*)&ctx[(((size_t)(b * H_DIM + h) * L_DIM + l) * HD + d)];
    uint2 p;
    p.x = f2bf(v.x) | (f2bf(v.y) << 16);
    p.y = f2bf(v.z) | (f2bf(v.w) << 16);
    ((uint2*)cb)[gid] = p;
}

// ---------------------------------------------------------------------------
// bf16 MFMA GEMM, 128x128 tile, BK=32, 4 waves. MODE 0: scatter q,k fp32 and
// v bf16 into [B,H,L,D] bufs. MODE 1: plain C+bias fp32.
// ---------------------------------------------------------------------------
template<int NCOLS, int MODE>
__global__ __launch_bounds__(256) void gemm_bt_kernel(
    const ushort_t* __restrict__ A, const ushort_t* __restrict__ BT,
    const float* __restrict__ bias,
    float* __restrict__ d0, float* __restrict__ d1, ushort_t* __restrict__ d2)
{
    __shared__ __align__(16) ushort_t Abuf[128 * 32];
    __shared__ __align__(16) ushort_t Bbuf[128 * 32];
    const int tid = threadIdx.x;
    const int wave = tid >> 6, lane = tid & 63;
    const int m0 = blockIdx.x * 128, n0 = blockIdx.y * 128;
    const int wr = (wave >> 1) * 64, wc = (wave & 1) * 64;
    const int g = lane >> 4, l15 = lane & 15;

    f32x4 acc[4][4];
    #pragma unroll
    for (int i = 0; i < 4; ++i)
        #pragma unroll
        for (int j = 0; j < 4; ++j) acc[i][j] = f32x4{0.f, 0.f, 0.f, 0.f};

    const int sr = tid >> 2;
    const int sc = (tid & 3) * 8;
    const ushort_t* Asrc0 = A + (size_t)(m0 + sr) * 1024 + sc;
    const ushort_t* Asrc1 = A + (size_t)(m0 + 64 + sr) * 1024 + sc;
    const ushort_t* Bsrc0 = BT + (size_t)(n0 + sr) * 1024 + sc;
    const ushort_t* Bsrc1 = BT + (size_t)(n0 + 64 + sr) * 1024 + sc;
    ushort_t* Adst0 = &Abuf[tid * 8];
    ushort_t* Adst1 = &Abuf[2048 + tid * 8];
    ushort_t* Bdst0 = &Bbuf[tid * 8];
    ushort_t* Bdst1 = &Bbuf[2048 + tid * 8];

    for (int k0 = 0; k0 < 1024; k0 += 32) {
        __syncthreads();
        gload16(Asrc0 + k0, Adst0);
        gload16(Asrc1 + k0, Adst1);
        gload16(Bsrc0 + k0, Bdst0);
        gload16(Bsrc1 + k0, Bdst1);
        __syncthreads();

        bf16x8 af[4];
        #pragma unroll
        for (int mt = 0; mt < 4; ++mt)
            af[mt] = *(const bf16x8*)&Abuf[(wr + mt * 16 + l15) * 32 + 8 * g];
        #pragma unroll
        for (int nt = 0; nt < 4; ++nt) {
            const bf16x8 bfr = *(const bf16x8*)&Bbuf[(wc + nt * 16 + l15) * 32 + 8 * g];
            #pragma unroll
            for (int mt = 0; mt < 4; ++mt)
                acc[mt][nt] = __builtin_amdgcn_mfma_f32_16x16x32_bf16(af[mt], bfr, acc[mt][nt], 0, 0, 0);
        }
    }

    #pragma unroll
    for (int nt = 0; nt < 4; ++nt) {
        const int n = n0 + wc + nt * 16 + l15;
        const float bv = bias[n];
        if (MODE == 0) {
            const int sel = n >> 10, h = (n & 1023) >> 6, d = n & 63;
            #pragma unroll
            for (int mt = 0; mt < 4; ++mt) {
                #pragma unroll
                for (int r = 0; r < 4; ++r) {
                    const int m = m0 + wr + mt * 16 + 4 * g + r;
                    const int bb = m >> 11, ll = m & 2047;
                    const size_t idx = ((size_t)((bb * H_DIM + h) * L_DIM + ll)) * HD + d;
                    const float val = acc[mt][nt][r] + bv;
                    if (sel == 0)      d0[idx] = val;
                    else if (sel == 1) d1[idx] = val;
                    else               d2[idx] = (ushort_t)f2bf(val);
                }
            }
        } else {
            #pragma unroll
            for (int mt = 0; mt < 4; ++mt) {
                #pragma unroll
                for (int r = 0; r < 4; ++r) {
                    const int m = m0 + wr + mt * 16 + 4 * g + r;
                    d0[(size_t)m * E_DIM + n] = acc[mt][nt][r] + bv;
                }
            }
        }
    }
}

// ---------------------------------------------------------------------------
// L2-normalize rows of fp32 [nrows][64], write bf16.
// ---------------------------------------------------------------------------
__global__ __launch_bounds__(256) void normalize_bf16_kernel(
    const float* __restrict__ in, ushort_t* __restrict__ out)
{
    const int r = blockIdx.x * 4 + (threadIdx.x >> 6);
    const int lane = threadIdx.x & 63;
    float v = in[(size_t)r * HD + lane];
    float s = v * v;
    #pragma unroll
    for (int m = 1; m < 64; m <<= 1) s += __shfl_xor(s, m);
    out[(size_t)r * HD + lane] = (ushort_t)f2bf(v * (1.0f / sqrtf(s)));
}

// ---------------------------------------------------------------------------
// transpose vb16 [bh][key][64] -> vt16 [bh][d][2048]
// ---------------------------------------------------------------------------
__global__ __launch_bounds__(256) void vt_transpose_kernel(
    const ushort_t* __restrict__ vb, ushort_t* __restrict__ vt)
{
    __shared__ ushort_t t[64][68];
    const int kt = blockIdx.x, bh = blockIdx.y;
    const int tid = threadIdx.x;
    const ushort_t* src = vb + ((size_t)bh * L_DIM + kt * 64) * HD;
    #pragma unroll
    for (int p = 0; p < 16; ++p) {
        const int idx = tid + 256 * p;
        t[idx >> 6][idx & 63] = src[idx];
    }
    __syncthreads();
    ushort_t* dst = vt + (size_t)bh * HD * L_DIM + kt * 64;
    #pragma unroll
    for (int p = 0; p < 16; ++p) {
        const int idx = tid + 256 * p;
        const int d = idx >> 6, k = idx & 63;
        dst[(size_t)d * L_DIM + k] = t[k][d];
    }
}

// ---------------------------------------------------------------------------
// MFMA flash attention v3. Block = 64 q-rows, 4 waves x 16 rows, kv tile 64.
// Double-buffered K/V staging (issue next tile before computing current, one
// barrier/iter). Fixed-shift softmax: m=8 (scores>=0, typically <<8) with a
// guarded full-rescale fallback via __any; l_i kept as per-lane partial and
// reduced once in the epilogue. P overlays the dead Q LDS rows of each wave.
// All LDS tiles XOR-swizzled (16B chunk ^= row&7), pre-swizzled global src.
// ---------------------------------------------------------------------------
__global__ __launch_bounds__(256) void attn_mfma_kernel(
    const ushort_t* __restrict__ qn, const ushort_t* __restrict__ kn,
    const ushort_t* __restrict__ vt, float* __restrict__ ctx)
{
    __shared__ __align__(16) ushort_t Qs[64 * 64];      // Q; reused as P after prologue
    __shared__ __align__(16) ushort_t Ks[2][64 * 64];
    __shared__ __align__(16) ushort_t Vs[2][64 * 64];

    const int qt = (L_DIM / 64 - 1) - blockIdx.x;   // 31..0, heavy first
    const int bh = blockIdx.y;
    const int q0 = qt * 64;
    const int tid = threadIdx.x, w = tid >> 6, lane = tid & 63;
    const int g = lane >> 4, l15 = lane & 15;
    ushort_t* Pw = &Qs[w * 16 * 64];                // wave's own dead Q rows

    const ushort_t* Qg = qn + ((size_t)bh * L_DIM + q0) * HD;
    const ushort_t* Kg = kn + (size_t)bh * L_DIM * HD;
    const ushort_t* Vg = vt + (size_t)bh * HD * L_DIM;

    const int srow = tid >> 3, sch = tid & 7;       // thread -> (row, 16B chunk)
    const int srow2 = (tid + 256) >> 3, sch2 = (tid + 256) & 7;

    // prologue: stage Q + K/V tile 0
    {
        gload16(Qg + srow * 64 + ((sch ^ (srow & 7)) << 3), Qs + srow * 64 + (sch << 3));
        gload16(Qg + srow2 * 64 + ((sch2 ^ (srow2 & 7)) << 3), Qs + srow2 * 64 + (sch2 << 3));
        gload16(Kg + (size_t)srow * 64 + ((sch ^ (srow & 7)) << 3), Ks[0] + srow * 64 + (sch << 3));
        gload16(Kg + (size_t)srow2 * 64 + ((sch2 ^ (srow2 & 7)) << 3), Ks[0] + srow2 * 64 + (sch2 << 3));
        gload16(Vg + (size_t)srow * L_DIM + ((sch ^ (srow & 7)) << 3), Vs[0] + srow * 64 + (sch << 3));
        gload16(Vg + (size_t)srow2 * L_DIM + ((sch2 ^ (srow2 & 7)) << 3), Vs[0] + srow2 * 64 + (sch2 << 3));
    }
    __syncthreads();

    // Q fragments (constant over key loop); wave w owns rows 16w..16w+15
    bf16x8 qf[2];
    #pragma unroll
    for (int kc = 0; kc < 2; ++kc) {
        const int row = 16 * w + l15;
        qf[kc] = *(const bf16x8*)&Qs[row * 64 + (((4 * kc + g) ^ (row & 7)) << 3)];
    }

    f32x4 o[4];
    float m_i = 8.0f, l_i = 0.f;    // fixed shift; scores >= 0, typ. << 8
    #pragma unroll
    for (int j = 0; j < 4; ++j) o[j] = f32x4{0.f, 0.f, 0.f, 0.f};

    const int nkt = qt + 1;
    for (int kt = 0; kt < nkt; ++kt) {
        const int cur = kt & 1;
        // issue next tile's staging first (latency hides under compute below)
        if (kt + 1 < nkt) {
            const int j1 = (kt + 1) * 64;
            gload16(Kg + (size_t)(j1 + srow) * 64 + ((sch ^ (srow & 7)) << 3),
                    Ks[cur ^ 1] + srow * 64 + (sch << 3));
            gload16(Kg + (size_t)(j1 + srow2) * 64 + ((sch2 ^ (srow2 & 7)) << 3),
                    Ks[cur ^ 1] + srow2 * 64 + (sch2 << 3));
            gload16(Vg + (size_t)srow * L_DIM + j1 + ((sch ^ (srow & 7)) << 3),
                    Vs[cur ^ 1] + srow * 64 + (sch << 3));
            gload16(Vg + (size_t)srow2 * L_DIM + j1 + ((sch2 ^ (srow2 & 7)) << 3),
                    Vs[cur ^ 1] + srow2 * 64 + (sch2 << 3));
        }
        const int j0 = kt * 64;

        // ---- S^T = K . Q^T ----
        bf16x8 ak[4][2];
        #pragma unroll
        for (int kt4 = 0; kt4 < 4; ++kt4)
            #pragma unroll
            for (int kc = 0; kc < 2; ++kc) {
                const int row = 16 * kt4 + l15;
                ak[kt4][kc] = *(const bf16x8*)&Ks[cur][row * 64 + (((4 * kc + g) ^ (row & 7)) << 3)];
            }
        f32x4 st[4];
        #pragma unroll
        for (int kt4 = 0; kt4 < 4; ++kt4) st[kt4] = f32x4{0.f, 0.f, 0.f, 0.f};
        #pragma unroll
        for (int kc = 0; kc < 2; ++kc)
            #pragma unroll
            for (int kt4 = 0; kt4 < 4; ++kt4)
                st[kt4] = __builtin_amdgcn_mfma_f32_16x16x32_bf16(
                    ak[kt4][kc], qf[kc], st[kt4], 0, 0, 0);

        // ---- score transform + mask; in-lane max only ----
        const int qrow = q0 + 16 * w + l15;
        float mx = 0.0f;
        #pragma unroll
        for (int kt4 = 0; kt4 < 4; ++kt4)
            #pragma unroll
            for (int r = 0; r < 4; ++r) {
                const int key = j0 + 16 * kt4 + 4 * g + r;
                const float x = st[kt4][r];
                float sc = __fdividef(x * x, C_CONST - 2.f * x);
                sc = (key > qrow) ? -1e30f : sc;
                st[kt4][r] = sc;
                mx = fmaxf(mx, sc);
            }

        // ---- rare fallback: a score exceeded the fixed shift ----
        if (__any(mx > m_i)) {
            mx = fmaxf(mx, __shfl_xor(mx, 16));
            mx = fmaxf(mx, __shfl_xor(mx, 32));
            const float newm = fmaxf(m_i, mx);
            const float scl = __expf(m_i - newm);
            l_i *= scl;
            #pragma unroll
            for (int r = 0; r < 4; ++r) {
                const float s = __shfl(scl, 4 * g + r);
                #pragma unroll
                for (int dt = 0; dt < 4; ++dt) o[dt][r] *= s;
            }
            m_i = newm;
        }

        // ---- P = exp(s - m); per-lane partial sum only ----
        float ts = 0.f;
        #pragma unroll
        for (int kt4 = 0; kt4 < 4; ++kt4)
            #pragma unroll
            for (int r = 0; r < 4; ++r) {
                const float pv = __expf(st[kt4][r] - m_i);
                st[kt4][r] = pv;
                ts += pv;
            }
        l_i += ts;

        // ---- pack P -> LDS (b64, 4 consecutive keys per lane) ----
        {
            const int qr = l15;
            #pragma unroll
            for (int kt4 = 0; kt4 < 4; ++kt4) {
                const int ch = 2 * kt4 + (g >> 1);
                uint2 pk;
                pk.x = f2bf(st[kt4][0]) | (f2bf(st[kt4][1]) << 16);
                pk.y = f2bf(st[kt4][2]) | (f2bf(st[kt4][3]) << 16);
                *(uint2*)&Pw[qr * 64 + ((ch ^ (qr & 7)) << 3) + 4 * (g & 1)] = pk;
            }
        }

        // ---- O += P . V ----
        bf16x8 ap[2], av[4][2];
        #pragma unroll
        for (int kc = 0; kc < 2; ++kc) {
            const int row = l15;
            ap[kc] = *(const bf16x8*)&Pw[row * 64 + (((4 * kc + g) ^ (row & 7)) << 3)];
        }
        #pragma unroll
        for (int dt = 0; dt < 4; ++dt)
            #pragma unroll
            for (int kc = 0; kc < 2; ++kc) {
                const int row = 16 * dt + l15;
                av[dt][kc] = *(const bf16x8*)&Vs[cur][row * 64 + (((4 * kc + g) ^ (row & 7)) << 3)];
            }
        #pragma unroll
        for (int kc = 0; kc < 2; ++kc)
            #pragma unroll
            for (int dt = 0; dt < 4; ++dt)
                o[dt] = __builtin_amdgcn_mfma_f32_16x16x32_bf16(
                    ap[kc], av[dt][kc], o[dt], 0, 0, 0);

        __syncthreads();   // drains next-tile staging; releases cur for reuse
    }

    // ---- epilogue: reduce l across lane groups, divide, store fp32 ctx ----
    l_i += __shfl_xor(l_i, 16);
    l_i += __shfl_xor(l_i, 32);
    float* Og = ctx + ((size_t)bh * L_DIM + q0 + 16 * w) * HD;
    #pragma unroll
    for (int r = 0; r < 4; ++r) {
        const float lv = __shfl(l_i, 4 * g + r);
        const float inv = 1.0f / lv;
        #pragma unroll
        for (int dt = 0; dt < 4; ++dt)
            Og[(size_t)(4 * g + r) * HD + 16 * dt + l15] = o[dt][r] * inv;
    }
}

// ---------------------------------------------------------------------------
extern "C" void kernel_launch(void* const* d_in, const int* in_sizes, int n_in,
                              void* d_out, int out_size, void* d_ws, size_t ws_size,
                              hipStream_t stream)
{
    const float* x    = (const float*)d_in[0];
    const float* Wqkv = (const float*)d_in[1];
    const float* bqkv = (const float*)d_in[2];
    const float* Wout = (const float*)d_in[3];
    const float* bout = (const float*)d_in[4];
    float* out = (float*)d_out;

    char* ws = (char*)d_ws;
    const size_t MB = 1u << 20;
    float*    qb    = (float*)   (ws + 0 * MB);    // [0,16) fp32 q
    float*    kb    = (float*)   (ws + 16 * MB);   // [16,32) fp32 k
    ushort_t* vb16  = (ushort_t*)(ws + 32 * MB);   // [32,40) bf16 v
    ushort_t* xb    = (ushort_t*)(ws + 40 * MB);   // [40,48) bf16 x     (dead after qkv gemm)
    ushort_t* WqkvT = (ushort_t*)(ws + 48 * MB);   // [48,54)            (dead after qkv gemm)
    ushort_t* kn16  = (ushort_t*)(ws + 40 * MB);   // reuse xb slot
    ushort_t* qn16  = (ushort_t*)(ws + 48 * MB);   // reuse WqkvT slot
    ushort_t* vt16  = (ushort_t*)(ws + 56 * MB);   // [56,64)
    float*    ctx   = (float*)   (ws + 0 * MB);    // reuse qb slot (qb dead after normalize)
    ushort_t* cb    = (ushort_t*)(ws + 16 * MB);   // reuse kb slot
    ushort_t* WoutT = (ushort_t*)(ws + 24 * MB);   // [24,26)

    // 1) bf16 copies for the qkv GEMM
    cast_bf16_kernel<<<4096, 256, 0, stream>>>(x, xb, (M_ROWS * E_DIM) / 4);
    transpose_bf16_kernel<<<dim3(QKV_N / 64, E_DIM / 64), 256, 0, stream>>>(Wqkv, WqkvT, E_DIM, QKV_N);

    // 2) qkv GEMM: q,k fp32; v bf16
    gemm_bt_kernel<QKV_N, 0><<<dim3(M_ROWS / 128, QKV_N / 128), 256, 0, stream>>>(
        xb, WqkvT, bqkv, qb, kb, vb16);

    // 3) normalize q,k -> bf16
    const int nrows = B_DIM * H_DIM * L_DIM;  // 65536
    normalize_bf16_kernel<<<nrows / 4, 256, 0, stream>>>(qb, qn16);
    normalize_bf16_kernel<<<nrows / 4, 256, 0, stream>>>(kb, kn16);

    // 4) transpose v -> vt16 [bh][d][key]
    vt_transpose_kernel<<<dim3(L_DIM / 64, B_DIM * H_DIM), 256, 0, stream>>>(vb16, vt16);

    // 5) MFMA flash attention (64-row q-tiles, heavy-first, double-buffered)
    attn_mfma_kernel<<<dim3(L_DIM / 64, B_DIM * H_DIM), 256, 0, stream>>>(qn16, kn16, vt16, ctx);

    // 6) gather ctx -> bf16 [M][E]; transpose W_out
    gather_ctx_kernel<<<4096, 256, 0, stream>>>(ctx, cb);
    transpose_bf16_kernel<<<dim3(E_DIM / 64, E_DIM / 64), 256, 0, stream>>>(Wout, WoutT, E_DIM, E_DIM);

    // 7) out = ctx @ W_out + b (MFMA)
    gemm_bt_kernel<E_DIM, 1><<<dim3(M_ROWS / 128, E_DIM / 128), 256, 0, stream>>>(
        cb, WoutT, bout, out, nullptr, nullptr);
}

// Round 11
// 159.605 us; speedup vs baseline: 1.5586x; 1.4107x over previous
//
#include <hip/hip_runtime.h>
#include <cstdint>
#include <cstddef>

// Problem dims (compile-time)
#define B_DIM 2
#define L_DIM 2048
#define E_DIM 1024
#define H_DIM 16
#define HD    64
#define M_ROWS (B_DIM * L_DIM)   // 4096
#define QKV_N  (3 * E_DIM)       // 3072
#define C_CONST 2.01f
#define NCH_BH 80                // chunks per bh: sum_qt ceil((qt+1)/8)

typedef unsigned short ushort_t;
typedef __attribute__((ext_vector_type(8))) short bf16x8;
typedef __attribute__((ext_vector_type(4))) float f32x4;

__device__ __forceinline__ unsigned int f2bf(float f) {
    union { float f; unsigned int u; } v; v.f = f;
    return (v.u + 0x7FFFu + ((v.u >> 16) & 1u)) >> 16;   // RNE
}
__device__ __forceinline__ float bf2f_lo(unsigned int u) {
    union { unsigned int u; float f; } v; v.u = u << 16; return v.f;
}
__device__ __forceinline__ float bf2f_hi(unsigned int u) {
    union { unsigned int u; float f; } v; v.u = u & 0xffff0000u; return v.f;
}

__device__ __forceinline__ void gload16(const void* g, void* l) {
    __builtin_amdgcn_global_load_lds(
        (const __attribute__((address_space(1))) void*)g,
        (__attribute__((address_space(3))) void*)l, 16, 0, 0);
}

// ---------------------------------------------------------------------------
// cast fp32 -> bf16 (contiguous), 4 elems/thread
// ---------------------------------------------------------------------------
__global__ __launch_bounds__(256) void cast_bf16_kernel(
    const float* __restrict__ in, ushort_t* __restrict__ out, int n4)
{
    const int i = blockIdx.x * 256 + threadIdx.x;
    if (i >= n4) return;
    const float4 v = ((const float4*)in)[i];
    uint2 p;
    p.x = f2bf(v.x) | (f2bf(v.y) << 16);
    p.y = f2bf(v.z) | (f2bf(v.w) << 16);
    ((uint2*)out)[i] = p;
}

// ---------------------------------------------------------------------------
// transpose fp32 [R][Cn] -> bf16 [Cn][R]
// ---------------------------------------------------------------------------
__global__ __launch_bounds__(256) void transpose_bf16_kernel(
    const float* __restrict__ in, ushort_t* __restrict__ out, int R, int Cn)
{
    __shared__ float t[64][65];
    const int c0 = blockIdx.x * 64, r0 = blockIdx.y * 64;
    const int tid = threadIdx.x;
    for (int idx = tid; idx < 4096; idx += 256) {
        const int r = idx >> 6, c = idx & 63;
        t[r][c] = in[(size_t)(r0 + r) * Cn + c0 + c];
    }
    __syncthreads();
    for (int idx = tid; idx < 4096; idx += 256) {
        const int c = idx >> 6, r = idx & 63;
        out[(size_t)(c0 + c) * R + r0 + r] = (ushort_t)f2bf(t[r][c]);
    }
}

// ---------------------------------------------------------------------------
// bf16 MFMA GEMM, 128x128 tile, BK=32, 4 waves.
// MODE 0: qkv; fused epilogue: q,k L2-normalized -> bf16 [bh][l][d];
//         v -> bf16 [bh][l][d].  MODE 1: plain C+bias fp32 [M][E].
// ---------------------------------------------------------------------------
template<int NCOLS, int MODE>
__global__ __launch_bounds__(256) void gemm_bt_kernel(
    const ushort_t* __restrict__ A, const ushort_t* __restrict__ BT,
    const float* __restrict__ bias, float* __restrict__ outf,
    ushort_t* __restrict__ q16, ushort_t* __restrict__ k16,
    ushort_t* __restrict__ v16)
{
    __shared__ __align__(16) ushort_t Abuf[128 * 32];
    __shared__ __align__(16) ushort_t Bbuf[128 * 32];
    const int tid = threadIdx.x;
    const int wave = tid >> 6, lane = tid & 63;
    const int m0 = blockIdx.x * 128, n0 = blockIdx.y * 128;
    const int wr = (wave >> 1) * 64, wc = (wave & 1) * 64;
    const int g = lane >> 4, l15 = lane & 15;

    f32x4 acc[4][4];
    #pragma unroll
    for (int i = 0; i < 4; ++i)
        #pragma unroll
        for (int j = 0; j < 4; ++j) acc[i][j] = f32x4{0.f, 0.f, 0.f, 0.f};

    const int sr = tid >> 2;
    const int sc = (tid & 3) * 8;
    const ushort_t* Asrc0 = A + (size_t)(m0 + sr) * 1024 + sc;
    const ushort_t* Asrc1 = A + (size_t)(m0 + 64 + sr) * 1024 + sc;
    const ushort_t* Bsrc0 = BT + (size_t)(n0 + sr) * 1024 + sc;
    const ushort_t* Bsrc1 = BT + (size_t)(n0 + 64 + sr) * 1024 + sc;
    ushort_t* Adst0 = &Abuf[tid * 8];
    ushort_t* Adst1 = &Abuf[2048 + tid * 8];
    ushort_t* Bdst0 = &Bbuf[tid * 8];
    ushort_t* Bdst1 = &Bbuf[2048 + tid * 8];

    for (int k0 = 0; k0 < 1024; k0 += 32) {
        __syncthreads();
        gload16(Asrc0 + k0, Adst0);
        gload16(Asrc1 + k0, Adst1);
        gload16(Bsrc0 + k0, Bdst0);
        gload16(Bsrc1 + k0, Bdst1);
        __syncthreads();

        bf16x8 af[4];
        #pragma unroll
        for (int mt = 0; mt < 4; ++mt)
            af[mt] = *(const bf16x8*)&Abuf[(wr + mt * 16 + l15) * 32 + 8 * g];
        #pragma unroll
        for (int nt = 0; nt < 4; ++nt) {
            const bf16x8 bfr = *(const bf16x8*)&Bbuf[(wc + nt * 16 + l15) * 32 + 8 * g];
            #pragma unroll
            for (int mt = 0; mt < 4; ++mt)
                acc[mt][nt] = __builtin_amdgcn_mfma_f32_16x16x32_bf16(af[mt], bfr, acc[mt][nt], 0, 0, 0);
        }
    }

    if (MODE == 0) {
        // wave's 64 cols = one (sel, h) head slice (n0 mult of 128, wc in {0,64})
        const int nBase = n0 + wc;
        const int sel = nBase >> 10;            // 0=q 1=k 2=v
        const int h   = (nBase & 1023) >> 6;
        float bv[4];
        #pragma unroll
        for (int nt = 0; nt < 4; ++nt) bv[nt] = bias[nBase + nt * 16 + l15];

        if (sel <= 1) {
            ushort_t* dst16 = (sel == 0) ? q16 : k16;
            #pragma unroll
            for (int mt = 0; mt < 4; ++mt) {
                float val[4][4], ss[4] = {0.f, 0.f, 0.f, 0.f};
                #pragma unroll
                for (int nt = 0; nt < 4; ++nt)
                    #pragma unroll
                    for (int r = 0; r < 4; ++r) {
                        const float v = acc[mt][nt][r] + bv[nt];
                        val[nt][r] = v;
                        ss[r] = fmaf(v, v, ss[r]);
                    }
                #pragma unroll
                for (int r = 0; r < 4; ++r) {   // reduce across l15 (same g-group)
                    float t = ss[r];
                    t += __shfl_xor(t, 1); t += __shfl_xor(t, 2);
                    t += __shfl_xor(t, 4); t += __shfl_xor(t, 8);
                    ss[r] = 1.0f / sqrtf(t);
                }
                #pragma unroll
                for (int r = 0; r < 4; ++r) {
                    const int m = m0 + wr + mt * 16 + 4 * g + r;
                    const int bb = m >> 11, ll = m & 2047;
                    ushort_t* base = dst16 + ((size_t)((bb * H_DIM + h) * L_DIM + ll)) * HD + l15;
                    #pragma unroll
                    for (int nt = 0; nt < 4; ++nt)
                        base[nt * 16] = (ushort_t)f2bf(val[nt][r] * ss[r]);
                }
            }
        } else {
            #pragma unroll
            for (int mt = 0; mt < 4; ++mt)
                #pragma unroll
                for (int r = 0; r < 4; ++r) {
                    const int m = m0 + wr + mt * 16 + 4 * g + r;
                    const int bb = m >> 11, ll = m & 2047;
                    ushort_t* base = v16 + ((size_t)((bb * H_DIM + h) * L_DIM + ll)) * HD + l15;
                    #pragma unroll
                    for (int nt = 0; nt < 4; ++nt)
                        base[nt * 16] = (ushort_t)f2bf(acc[mt][nt][r] + bv[nt]);
                }
        }
    } else {
        #pragma unroll
        for (int nt = 0; nt < 4; ++nt) {
            const int n = n0 + wc + nt * 16 + l15;
            const float bvv = bias[n];
            #pragma unroll
            for (int mt = 0; mt < 4; ++mt)
                #pragma unroll
                for (int r = 0; r < 4; ++r) {
                    const int m = m0 + wr + mt * 16 + 4 * g + r;
                    outf[(size_t)m * E_DIM + n] = acc[mt][nt][r] + bvv;
                }
        }
    }
}

// ---------------------------------------------------------------------------
// transpose vb16 [bh][key][64] -> vt16 [bh][d][2048]
// ---------------------------------------------------------------------------
__global__ __launch_bounds__(256) void vt_transpose_kernel(
    const ushort_t* __restrict__ vb, ushort_t* __restrict__ vt)
{
    __shared__ ushort_t t[64][68];
    const int kt = blockIdx.x, bh = blockIdx.y;
    const int tid = threadIdx.x;
    const ushort_t* src = vb + ((size_t)bh * L_DIM + kt * 64) * HD;
    #pragma unroll
    for (int p = 0; p < 16; ++p) {
        const int idx = tid + 256 * p;
        t[idx >> 6][idx & 63] = src[idx];
    }
    __syncthreads();
    ushort_t* dst = vt + (size_t)bh * HD * L_DIM + kt * 64;
    #pragma unroll
    for (int p = 0; p < 16; ++p) {
        const int idx = tid + 256 * p;
        const int d = idx >> 6, k = idx & 63;
        dst[(size_t)d * L_DIM + k] = t[k][d];
    }
}

// ---------------------------------------------------------------------------
// Split-K MFMA flash attention. Block = chunk (qt, s): 64 q-rows x <=8 kv
// tiles of 64 keys. 4 waves x 16 q-rows. Double-buffered K/V. Fixed-shift
// softmax m=8 (scores>=0) with guarded rescale fallback. Emits partials:
// pO bf16 [cid][64 rows][64 d], pl/pm fp32 [cid][64].
// ---------------------------------------------------------------------------
__global__ __launch_bounds__(256) void attn_mfma_kernel(
    const ushort_t* __restrict__ qn, const ushort_t* __restrict__ kn,
    const ushort_t* __restrict__ vt,
    ushort_t* __restrict__ pO, float* __restrict__ pl, float* __restrict__ pm)
{
    __shared__ __align__(16) ushort_t Qs[64 * 64];      // Q; reused as P
    __shared__ __align__(16) ushort_t Ks[2][64 * 64];
    __shared__ __align__(16) ushort_t Vs[2][64 * 64];

    // decode chunk id -> (qt, s)
    int c = blockIdx.x, qt = 0, s = 0;
    #pragma unroll
    for (int gg = 0; gg < 4; ++gg) {
        const int sz = 8 * (gg + 1);
        if (c < sz) { qt = 8 * gg + c / (gg + 1); s = c - (c / (gg + 1)) * (gg + 1); break; }
        c -= sz;
    }
    const int bh = blockIdx.y;
    const int cid = bh * NCH_BH + blockIdx.x;
    const int q0 = qt * 64;
    const int kt0 = 8 * s;
    const int ktEnd = min(8 * s + 8, qt + 1);

    const int tid = threadIdx.x, w = tid >> 6, lane = tid & 63;
    const int g = lane >> 4, l15 = lane & 15;
    ushort_t* Pw = &Qs[w * 16 * 64];                // wave's own dead Q rows

    const ushort_t* Qg = qn + ((size_t)bh * L_DIM + q0) * HD;
    const ushort_t* Kg = kn + (size_t)bh * L_DIM * HD;
    const ushort_t* Vg = vt + (size_t)bh * HD * L_DIM;

    const int srow = tid >> 3, sch = tid & 7;
    const int srow2 = (tid + 256) >> 3, sch2 = (tid + 256) & 7;

    // prologue: stage Q + K/V tile kt0
    {
        const int j0 = kt0 * 64;
        gload16(Qg + srow * 64 + ((sch ^ (srow & 7)) << 3), Qs + srow * 64 + (sch << 3));
        gload16(Qg + srow2 * 64 + ((sch2 ^ (srow2 & 7)) << 3), Qs + srow2 * 64 + (sch2 << 3));
        gload16(Kg + (size_t)(j0 + srow) * 64 + ((sch ^ (srow & 7)) << 3), Ks[0] + srow * 64 + (sch << 3));
        gload16(Kg + (size_t)(j0 + srow2) * 64 + ((sch2 ^ (srow2 & 7)) << 3), Ks[0] + srow2 * 64 + (sch2 << 3));
        gload16(Vg + (size_t)srow * L_DIM + j0 + ((sch ^ (srow & 7)) << 3), Vs[0] + srow * 64 + (sch << 3));
        gload16(Vg + (size_t)srow2 * L_DIM + j0 + ((sch2 ^ (srow2 & 7)) << 3), Vs[0] + srow2 * 64 + (sch2 << 3));
    }
    __syncthreads();

    bf16x8 qf[2];
    #pragma unroll
    for (int kc = 0; kc < 2; ++kc) {
        const int row = 16 * w + l15;
        qf[kc] = *(const bf16x8*)&Qs[row * 64 + (((4 * kc + g) ^ (row & 7)) << 3)];
    }

    f32x4 o[4];
    float m_i = 8.0f, l_i = 0.f;
    #pragma unroll
    for (int j = 0; j < 4; ++j) o[j] = f32x4{0.f, 0.f, 0.f, 0.f};

    for (int kt = kt0; kt < ktEnd; ++kt) {
        const int cur = (kt - kt0) & 1;
        if (kt + 1 < ktEnd) {
            const int j1 = (kt + 1) * 64;
            gload16(Kg + (size_t)(j1 + srow) * 64 + ((sch ^ (srow & 7)) << 3),
                    Ks[cur ^ 1] + srow * 64 + (sch << 3));
            gload16(Kg + (size_t)(j1 + srow2) * 64 + ((sch2 ^ (srow2 & 7)) << 3),
                    Ks[cur ^ 1] + srow2 * 64 + (sch2 << 3));
            gload16(Vg + (size_t)srow * L_DIM + j1 + ((sch ^ (srow & 7)) << 3),
                    Vs[cur ^ 1] + srow * 64 + (sch << 3));
            gload16(Vg + (size_t)srow2 * L_DIM + j1 + ((sch2 ^ (srow2 & 7)) << 3),
                    Vs[cur ^ 1] + srow2 * 64 + (sch2 << 3));
        }
        const int j0 = kt * 64;

        // ---- S^T = K . Q^T ----
        bf16x8 ak[4][2];
        #pragma unroll
        for (int kt4 = 0; kt4 < 4; ++kt4)
            #pragma unroll
            for (int kc = 0; kc < 2; ++kc) {
                const int row = 16 * kt4 + l15;
                ak[kt4][kc] = *(const bf16x8*)&Ks[cur][row * 64 + (((4 * kc + g) ^ (row & 7)) << 3)];
            }
        f32x4 st[4];
        #pragma unroll
        for (int kt4 = 0; kt4 < 4; ++kt4) st[kt4] = f32x4{0.f, 0.f, 0.f, 0.f};
        __builtin_amdgcn_s_setprio(1);
        #pragma unroll
        for (int kc = 0; kc < 2; ++kc)
            #pragma unroll
            for (int kt4 = 0; kt4 < 4; ++kt4)
                st[kt4] = __builtin_amdgcn_mfma_f32_16x16x32_bf16(
                    ak[kt4][kc], qf[kc], st[kt4], 0, 0, 0);
        __builtin_amdgcn_s_setprio(0);

        // ---- score transform + mask; in-lane max ----
        const int qrow = q0 + 16 * w + l15;
        const bool diag = (kt == qt);
        float mx = 0.0f;
        #pragma unroll
        for (int kt4 = 0; kt4 < 4; ++kt4)
            #pragma unroll
            for (int r = 0; r < 4; ++r) {
                const int key = j0 + 16 * kt4 + 4 * g + r;
                const float x = st[kt4][r];
                float sc = __fdividef(x * x, C_CONST - 2.f * x);
                sc = (diag && key > qrow) ? -1e30f : sc;
                st[kt4][r] = sc;
                mx = fmaxf(mx, sc);
            }

        if (__any(mx > m_i)) {   // rare: score exceeded fixed shift
            mx = fmaxf(mx, __shfl_xor(mx, 16));
            mx = fmaxf(mx, __shfl_xor(mx, 32));
            const float newm = fmaxf(m_i, mx);
            const float scl = __expf(m_i - newm);
            l_i *= scl;
            #pragma unroll
            for (int r = 0; r < 4; ++r) {
                const float sv = __shfl(scl, 4 * g + r);
                #pragma unroll
                for (int dt = 0; dt < 4; ++dt) o[dt][r] *= sv;
            }
            m_i = newm;
        }

        float ts = 0.f;
        #pragma unroll
        for (int kt4 = 0; kt4 < 4; ++kt4)
            #pragma unroll
            for (int r = 0; r < 4; ++r) {
                const float pv = __expf(st[kt4][r] - m_i);
                st[kt4][r] = pv;
                ts += pv;
            }
        l_i += ts;

        // ---- pack P -> LDS (b64) ----
        {
            const int qr = l15;
            #pragma unroll
            for (int kt4 = 0; kt4 < 4; ++kt4) {
                const int ch = 2 * kt4 + (g >> 1);
                uint2 pk;
                pk.x = f2bf(st[kt4][0]) | (f2bf(st[kt4][1]) << 16);
                pk.y = f2bf(st[kt4][2]) | (f2bf(st[kt4][3]) << 16);
                *(uint2*)&Pw[qr * 64 + ((ch ^ (qr & 7)) << 3) + 4 * (g & 1)] = pk;
            }
        }

        // ---- O += P . V ----
        bf16x8 ap[2], av[4][2];
        #pragma unroll
        for (int kc = 0; kc < 2; ++kc)
            ap[kc] = *(const bf16x8*)&Pw[l15 * 64 + (((4 * kc + g) ^ (l15 & 7)) << 3)];
        #pragma unroll
        for (int dt = 0; dt < 4; ++dt)
            #pragma unroll
            for (int kc = 0; kc < 2; ++kc) {
                const int row = 16 * dt + l15;
                av[dt][kc] = *(const bf16x8*)&Vs[cur][row * 64 + (((4 * kc + g) ^ (row & 7)) << 3)];
            }
        __builtin_amdgcn_s_setprio(1);
        #pragma unroll
        for (int kc = 0; kc < 2; ++kc)
            #pragma unroll
            for (int dt = 0; dt < 4; ++dt)
                o[dt] = __builtin_amdgcn_mfma_f32_16x16x32_bf16(
                    ap[kc], av[dt][kc], o[dt], 0, 0, 0);
        __builtin_amdgcn_s_setprio(0);

        __syncthreads();   // drains next-tile staging; releases cur buffer
    }

    // ---- epilogue: write partials (no divide) ----
    l_i += __shfl_xor(l_i, 16);
    l_i += __shfl_xor(l_i, 32);
    ushort_t* po = pO + (size_t)cid * 4096 + (16 * w) * 64;
    #pragma unroll
    for (int r = 0; r < 4; ++r)
        #pragma unroll
        for (int dt = 0; dt < 4; ++dt)
            po[(4 * g + r) * 64 + 16 * dt + l15] = (ushort_t)f2bf(o[dt][r]);
    if (lane < 16) {
        pl[cid * 64 + 16 * w + lane] = l_i;
        pm[cid * 64 + 16 * w + lane] = m_i;
    }
}

// ---------------------------------------------------------------------------
// combine: merge <=4 chunk partials per (bh, qt); divide; write cb [M][E] bf16
// ---------------------------------------------------------------------------
__global__ __launch_bounds__(256) void combine_kernel(
    const ushort_t* __restrict__ pO, const float* __restrict__ pl,
    const float* __restrict__ pm, ushort_t* __restrict__ cb)
{
    const int qt = blockIdx.x, bh = blockIdx.y;
    const int gg = qt >> 3, ns = gg + 1;
    const int cid0 = bh * NCH_BH + 4 * gg * (gg + 1) + (qt & 7) * (gg + 1);
    const int tid = threadIdx.x;
    const int row = tid >> 2, seg = tid & 3;

    float mt = -1e30f;
    for (int s2 = 0; s2 < ns; ++s2)
        mt = fmaxf(mt, pm[(cid0 + s2) * 64 + row]);

    float acc[16];
    #pragma unroll
    for (int j = 0; j < 16; ++j) acc[j] = 0.f;
    float l_tot = 0.f;
    for (int s2 = 0; s2 < ns; ++s2) {
        const int cid = cid0 + s2;
        const float sc = __expf(pm[cid * 64 + row] - mt);
        l_tot += pl[cid * 64 + row] * sc;
        const ushort_t* src = pO + (size_t)cid * 4096 + row * 64 + seg * 16;
        const uint4 u0 = *(const uint4*)src;
        const uint4 u1 = *(const uint4*)(src + 8);
        const unsigned int uu[8] = {u0.x, u0.y, u0.z, u0.w, u1.x, u1.y, u1.z, u1.w};
        #pragma unroll
        for (int j = 0; j < 8; ++j) {
            acc[2 * j]     = fmaf(sc, bf2f_lo(uu[j]), acc[2 * j]);
            acc[2 * j + 1] = fmaf(sc, bf2f_hi(uu[j]), acc[2 * j + 1]);
        }
    }
    const float inv = 1.0f / l_tot;
    const int b = bh >> 4, h = bh & 15;
    ushort_t* dst = cb + ((size_t)(b * L_DIM + qt * 64 + row)) * E_DIM + h * HD + seg * 16;
    uint4 w0, w1;
    w0.x = f2bf(acc[0] * inv)  | (f2bf(acc[1] * inv) << 16);
    w0.y = f2bf(acc[2] * inv)  | (f2bf(acc[3] * inv) << 16);
    w0.z = f2bf(acc[4] * inv)  | (f2bf(acc[5] * inv) << 16);
    w0.w = f2bf(acc[6] * inv)  | (f2bf(acc[7] * inv) << 16);
    w1.x = f2bf(acc[8] * inv)  | (f2bf(acc[9] * inv) << 16);
    w1.y = f2bf(acc[10] * inv) | (f2bf(acc[11] * inv) << 16);
    w1.z = f2bf(acc[12] * inv) | (f2bf(acc[13] * inv) << 16);
    w1.w = f2bf(acc[14] * inv) | (f2bf(acc[15] * inv) << 16);
    *(uint4*)dst = w0;
    *(uint4*)(dst + 8) = w1;
}

// ---------------------------------------------------------------------------
extern "C" void kernel_launch(void* const* d_in, const int* in_sizes, int n_in,
                              void* d_out, int out_size, void* d_ws, size_t ws_size,
                              hipStream_t stream)
{
    const float* x    = (const float*)d_in[0];
    const float* Wqkv = (const float*)d_in[1];
    const float* bqkv = (const float*)d_in[2];
    const float* Wout = (const float*)d_in[3];
    const float* bout = (const float*)d_in[4];
    float* out = (float*)d_out;

    char* ws = (char*)d_ws;
    const size_t MB = 1u << 20;
    ushort_t* qn16  = (ushort_t*)(ws + 0 * MB);    // [0,8)
    ushort_t* kn16  = (ushort_t*)(ws + 8 * MB);    // [8,16)
    ushort_t* vb16  = (ushort_t*)(ws + 16 * MB);   // [16,24) dead after vt_transpose
    ushort_t* vt16  = (ushort_t*)(ws + 24 * MB);   // [24,32)
    ushort_t* xb    = (ushort_t*)(ws + 32 * MB);   // [32,40) dead after qkv gemm
    ushort_t* cb    = (ushort_t*)(ws + 32 * MB);   // reuse xb slot
    ushort_t* WqkvT = (ushort_t*)(ws + 40 * MB);   // [40,46) dead after qkv gemm
    ushort_t* pO    = (ushort_t*)(ws + 40 * MB);   // [40,60) 2560 x 8KB (reuse WqkvT+)
    float*    pl    = (float*)   (ws + 60 * MB);   // [60,60.66)
    float*    pm    = (float*)   (ws + 61 * MB);   // [61,61.66)
    ushort_t* WoutT = (ushort_t*)(ws + 62 * MB);   // [62,64)

    // 1) bf16 copies for the qkv GEMM
    cast_bf16_kernel<<<4096, 256, 0, stream>>>(x, xb, (M_ROWS * E_DIM) / 4);
    transpose_bf16_kernel<<<dim3(QKV_N / 64, E_DIM / 64), 256, 0, stream>>>(Wqkv, WqkvT, E_DIM, QKV_N);

    // 2) qkv GEMM with fused normalize: qn16, kn16, vb16
    gemm_bt_kernel<QKV_N, 0><<<dim3(M_ROWS / 128, QKV_N / 128), 256, 0, stream>>>(
        xb, WqkvT, bqkv, nullptr, qn16, kn16, vb16);

    // 3) transpose v -> vt16 [bh][d][key]
    vt_transpose_kernel<<<dim3(L_DIM / 64, B_DIM * H_DIM), 256, 0, stream>>>(vb16, vt16);

    // 4) W_out transpose (independent)
    transpose_bf16_kernel<<<dim3(E_DIM / 64, E_DIM / 64), 256, 0, stream>>>(Wout, WoutT, E_DIM, E_DIM);

    // 5) split-K MFMA flash attention -> partials
    attn_mfma_kernel<<<dim3(NCH_BH, B_DIM * H_DIM), 256, 0, stream>>>(qn16, kn16, vt16, pO, pl, pm);

    // 6) combine partials -> cb [M][E] bf16
    combine_kernel<<<dim3(L_DIM / 64, B_DIM * H_DIM), 256, 0, stream>>>(pO, pl, pm, cb);

    // 7) out = ctx @ W_out + b (MFMA)
    gemm_bt_kernel<E_DIM, 1><<<dim3(M_ROWS / 128, E_DIM / 128), 256, 0, stream>>>(
        cb, WoutT, bout, out, nullptr, nullptr, nullptr);
}

// Round 12
// 129.710 us; speedup vs baseline: 1.9178x; 1.2305x over previous
//
#include <hip/hip_runtime.h>
#include <cstdint>
#include <cstddef>

// Problem dims (compile-time)
#define B_DIM 2
#define L_DIM 2048
#define E_DIM 1024
#define H_DIM 16
#define HD    64
#define M_ROWS (B_DIM * L_DIM)   // 4096
#define QKV_N  (3 * E_DIM)       // 3072
#define C_CONST 2.01f
#define NCH_BH 80                // chunks per bh: sum_qt ceil((qt+1)/8)
#define LOG2E 1.4426950408889634f
#define LN2   0.6931471805599453f

typedef unsigned short ushort_t;
typedef __attribute__((ext_vector_type(8))) short bf16x8;
typedef __attribute__((ext_vector_type(4))) float f32x4;

__device__ __forceinline__ unsigned int f2bf(float f) {
    union { float f; unsigned int u; } v; v.f = f;
    return (v.u + 0x7FFFu + ((v.u >> 16) & 1u)) >> 16;   // RNE
}
__device__ __forceinline__ float bf2f_lo(unsigned int u) {
    union { unsigned int u; float f; } v; v.u = u << 16; return v.f;
}
__device__ __forceinline__ float bf2f_hi(unsigned int u) {
    union { unsigned int u; float f; } v; v.u = u & 0xffff0000u; return v.f;
}

__device__ __forceinline__ void gload16(const void* g, void* l) {
    __builtin_amdgcn_global_load_lds(
        (const __attribute__((address_space(1))) void*)g,
        (__attribute__((address_space(3))) void*)l, 16, 0, 0);
}

// ---------------------------------------------------------------------------
// cast fp32 -> bf16 (contiguous), 4 elems/thread
// ---------------------------------------------------------------------------
__global__ __launch_bounds__(256) void cast_bf16_kernel(
    const float* __restrict__ in, ushort_t* __restrict__ out, int n4)
{
    const int i = blockIdx.x * 256 + threadIdx.x;
    if (i >= n4) return;
    const float4 v = ((const float4*)in)[i];
    uint2 p;
    p.x = f2bf(v.x) | (f2bf(v.y) << 16);
    p.y = f2bf(v.z) | (f2bf(v.w) << 16);
    ((uint2*)out)[i] = p;
}

// ---------------------------------------------------------------------------
// transpose fp32 [R][Cn] -> bf16 [Cn][R]
// ---------------------------------------------------------------------------
__global__ __launch_bounds__(256) void transpose_bf16_kernel(
    const float* __restrict__ in, ushort_t* __restrict__ out, int R, int Cn)
{
    __shared__ float t[64][65];
    const int c0 = blockIdx.x * 64, r0 = blockIdx.y * 64;
    const int tid = threadIdx.x;
    for (int idx = tid; idx < 4096; idx += 256) {
        const int r = idx >> 6, c = idx & 63;
        t[r][c] = in[(size_t)(r0 + r) * Cn + c0 + c];
    }
    __syncthreads();
    for (int idx = tid; idx < 4096; idx += 256) {
        const int c = idx >> 6, r = idx & 63;
        out[(size_t)(c0 + c) * R + r0 + r] = (ushort_t)f2bf(t[r][c]);
    }
}

// ---------------------------------------------------------------------------
// bf16 MFMA GEMM, 128x128 tile, BK=32, 4 waves.
// MODE 0: qkv; fused epilogue: q,k L2-normalized -> bf16 [bh][l][d];
//         v -> bf16 [bh][l][d].  MODE 1: plain C+bias fp32 [M][E].
// ---------------------------------------------------------------------------
template<int NCOLS, int MODE>
__global__ __launch_bounds__(256) void gemm_bt_kernel(
    const ushort_t* __restrict__ A, const ushort_t* __restrict__ BT,
    const float* __restrict__ bias, float* __restrict__ outf,
    ushort_t* __restrict__ q16, ushort_t* __restrict__ k16,
    ushort_t* __restrict__ v16)
{
    __shared__ __align__(16) ushort_t Abuf[128 * 32];
    __shared__ __align__(16) ushort_t Bbuf[128 * 32];
    const int tid = threadIdx.x;
    const int wave = tid >> 6, lane = tid & 63;
    const int m0 = blockIdx.x * 128, n0 = blockIdx.y * 128;
    const int wr = (wave >> 1) * 64, wc = (wave & 1) * 64;
    const int g = lane >> 4, l15 = lane & 15;

    f32x4 acc[4][4];
    #pragma unroll
    for (int i = 0; i < 4; ++i)
        #pragma unroll
        for (int j = 0; j < 4; ++j) acc[i][j] = f32x4{0.f, 0.f, 0.f, 0.f};

    const int sr = tid >> 2;
    const int sc = (tid & 3) * 8;
    const ushort_t* Asrc0 = A + (size_t)(m0 + sr) * 1024 + sc;
    const ushort_t* Asrc1 = A + (size_t)(m0 + 64 + sr) * 1024 + sc;
    const ushort_t* Bsrc0 = BT + (size_t)(n0 + sr) * 1024 + sc;
    const ushort_t* Bsrc1 = BT + (size_t)(n0 + 64 + sr) * 1024 + sc;
    ushort_t* Adst0 = &Abuf[tid * 8];
    ushort_t* Adst1 = &Abuf[2048 + tid * 8];
    ushort_t* Bdst0 = &Bbuf[tid * 8];
    ushort_t* Bdst1 = &Bbuf[2048 + tid * 8];

    for (int k0 = 0; k0 < 1024; k0 += 32) {
        __syncthreads();
        gload16(Asrc0 + k0, Adst0);
        gload16(Asrc1 + k0, Adst1);
        gload16(Bsrc0 + k0, Bdst0);
        gload16(Bsrc1 + k0, Bdst1);
        __syncthreads();

        bf16x8 af[4];
        #pragma unroll
        for (int mt = 0; mt < 4; ++mt)
            af[mt] = *(const bf16x8*)&Abuf[(wr + mt * 16 + l15) * 32 + 8 * g];
        #pragma unroll
        for (int nt = 0; nt < 4; ++nt) {
            const bf16x8 bfr = *(const bf16x8*)&Bbuf[(wc + nt * 16 + l15) * 32 + 8 * g];
            #pragma unroll
            for (int mt = 0; mt < 4; ++mt)
                acc[mt][nt] = __builtin_amdgcn_mfma_f32_16x16x32_bf16(af[mt], bfr, acc[mt][nt], 0, 0, 0);
        }
    }

    if (MODE == 0) {
        // wave's 64 cols = one (sel, h) head slice (n0 mult of 128, wc in {0,64})
        const int nBase = n0 + wc;
        const int sel = nBase >> 10;            // 0=q 1=k 2=v
        const int h   = (nBase & 1023) >> 6;
        float bv[4];
        #pragma unroll
        for (int nt = 0; nt < 4; ++nt) bv[nt] = bias[nBase + nt * 16 + l15];

        if (sel <= 1) {
            ushort_t* dst16 = (sel == 0) ? q16 : k16;
            #pragma unroll
            for (int mt = 0; mt < 4; ++mt) {
                float val[4][4], ss[4] = {0.f, 0.f, 0.f, 0.f};
                #pragma unroll
                for (int nt = 0; nt < 4; ++nt)
                    #pragma unroll
                    for (int r = 0; r < 4; ++r) {
                        const float v = acc[mt][nt][r] + bv[nt];
                        val[nt][r] = v;
                        ss[r] = fmaf(v, v, ss[r]);
                    }
                #pragma unroll
                for (int r = 0; r < 4; ++r) {   // reduce across l15 (same g-group)
                    float t = ss[r];
                    t += __shfl_xor(t, 1); t += __shfl_xor(t, 2);
                    t += __shfl_xor(t, 4); t += __shfl_xor(t, 8);
                    ss[r] = 1.0f / sqrtf(t);
                }
                #pragma unroll
                for (int r = 0; r < 4; ++r) {
                    const int m = m0 + wr + mt * 16 + 4 * g + r;
                    const int bb = m >> 11, ll = m & 2047;
                    ushort_t* base = dst16 + ((size_t)((bb * H_DIM + h) * L_DIM + ll)) * HD + l15;
                    #pragma unroll
                    for (int nt = 0; nt < 4; ++nt)
                        base[nt * 16] = (ushort_t)f2bf(val[nt][r] * ss[r]);
                }
            }
        } else {
            #pragma unroll
            for (int mt = 0; mt < 4; ++mt)
                #pragma unroll
                for (int r = 0; r < 4; ++r) {
                    const int m = m0 + wr + mt * 16 + 4 * g + r;
                    const int bb = m >> 11, ll = m & 2047;
                    ushort_t* base = v16 + ((size_t)((bb * H_DIM + h) * L_DIM + ll)) * HD + l15;
                    #pragma unroll
                    for (int nt = 0; nt < 4; ++nt)
                        base[nt * 16] = (ushort_t)f2bf(acc[mt][nt][r] + bv[nt]);
                }
        }
    } else {
        #pragma unroll
        for (int nt = 0; nt < 4; ++nt) {
            const int n = n0 + wc + nt * 16 + l15;
            const float bvv = bias[n];
            #pragma unroll
            for (int mt = 0; mt < 4; ++mt)
                #pragma unroll
                for (int r = 0; r < 4; ++r) {
                    const int m = m0 + wr + mt * 16 + 4 * g + r;
                    outf[(size_t)m * E_DIM + n] = acc[mt][nt][r] + bvv;
                }
        }
    }
}

// ---------------------------------------------------------------------------
// transpose vb16 [bh][key][64] -> vt16 [bh][d][2048]
// ---------------------------------------------------------------------------
__global__ __launch_bounds__(256) void vt_transpose_kernel(
    const ushort_t* __restrict__ vb, ushort_t* __restrict__ vt)
{
    __shared__ ushort_t t[64][68];
    const int kt = blockIdx.x, bh = blockIdx.y;
    const int tid = threadIdx.x;
    const ushort_t* src = vb + ((size_t)bh * L_DIM + kt * 64) * HD;
    #pragma unroll
    for (int p = 0; p < 16; ++p) {
        const int idx = tid + 256 * p;
        t[idx >> 6][idx & 63] = src[idx];
    }
    __syncthreads();
    ushort_t* dst = vt + (size_t)bh * HD * L_DIM + kt * 64;
    #pragma unroll
    for (int p = 0; p < 16; ++p) {
        const int idx = tid + 256 * p;
        const int d = idx >> 6, k = idx & 63;
        dst[(size_t)d * L_DIM + k] = t[k][d];
    }
}

// ---------------------------------------------------------------------------
// Split-K MFMA flash attention, log2-domain softmax. Block = chunk (qt, s):
// 64 q-rows x <=8 kv tiles of 64 keys. 4 waves x 16 q-rows. Double-buffered
// K/V. Fixed shift M = 8*log2e in exp2 domain; guarded rescale fallback.
// Scores e = (x^2*log2e)*rcp(C-2x) - M; p = v_exp(e); pack via cvt_pk.
// Emits partials: pO bf16 [cid][64 rows][64 d], pl/pm fp32 [cid][64].
// ---------------------------------------------------------------------------
__global__ __launch_bounds__(256) void attn_mfma_kernel(
    const ushort_t* __restrict__ qn, const ushort_t* __restrict__ kn,
    const ushort_t* __restrict__ vt,
    ushort_t* __restrict__ pO, float* __restrict__ pl, float* __restrict__ pm)
{
    __shared__ __align__(16) ushort_t Qs[64 * 64];      // Q; reused as P
    __shared__ __align__(16) ushort_t Ks[2][64 * 64];
    __shared__ __align__(16) ushort_t Vs[2][64 * 64];

    // decode chunk id -> (qt, s)
    int c = blockIdx.x, qt = 0, s = 0;
    #pragma unroll
    for (int gg = 0; gg < 4; ++gg) {
        const int sz = 8 * (gg + 1);
        if (c < sz) { qt = 8 * gg + c / (gg + 1); s = c - (c / (gg + 1)) * (gg + 1); break; }
        c -= sz;
    }
    const int bh = blockIdx.y;
    const int cid = bh * NCH_BH + blockIdx.x;
    const int q0 = qt * 64;
    const int kt0 = 8 * s;
    const int ktEnd = min(8 * s + 8, qt + 1);

    const int tid = threadIdx.x, w = tid >> 6, lane = tid & 63;
    const int g = lane >> 4, l15 = lane & 15;
    ushort_t* Pw = &Qs[w * 16 * 64];                // wave's own dead Q rows

    const ushort_t* Qg = qn + ((size_t)bh * L_DIM + q0) * HD;
    const ushort_t* Kg = kn + (size_t)bh * L_DIM * HD;
    const ushort_t* Vg = vt + (size_t)bh * HD * L_DIM;

    const int srow = tid >> 3, sch = tid & 7;
    const int srow2 = (tid + 256) >> 3, sch2 = (tid + 256) & 7;

    // prologue: stage Q + K/V tile kt0
    {
        const int j0 = kt0 * 64;
        gload16(Qg + srow * 64 + ((sch ^ (srow & 7)) << 3), Qs + srow * 64 + (sch << 3));
        gload16(Qg + srow2 * 64 + ((sch2 ^ (srow2 & 7)) << 3), Qs + srow2 * 64 + (sch2 << 3));
        gload16(Kg + (size_t)(j0 + srow) * 64 + ((sch ^ (srow & 7)) << 3), Ks[0] + srow * 64 + (sch << 3));
        gload16(Kg + (size_t)(j0 + srow2) * 64 + ((sch2 ^ (srow2 & 7)) << 3), Ks[0] + srow2 * 64 + (sch2 << 3));
        gload16(Vg + (size_t)srow * L_DIM + j0 + ((sch ^ (srow & 7)) << 3), Vs[0] + srow * 64 + (sch << 3));
        gload16(Vg + (size_t)srow2 * L_DIM + j0 + ((sch2 ^ (srow2 & 7)) << 3), Vs[0] + srow2 * 64 + (sch2 << 3));
    }
    __syncthreads();

    bf16x8 qf[2];
    #pragma unroll
    for (int kc = 0; kc < 2; ++kc) {
        const int row = 16 * w + l15;
        qf[kc] = *(const bf16x8*)&Qs[row * 64 + (((4 * kc + g) ^ (row & 7)) << 3)];
    }

    f32x4 o[4];
    float M = 8.0f * LOG2E, l_i = 0.f;   // shift in log2 domain
    #pragma unroll
    for (int j = 0; j < 4; ++j) o[j] = f32x4{0.f, 0.f, 0.f, 0.f};

    const int qrow = q0 + 16 * w + l15;

    for (int kt = kt0; kt < ktEnd; ++kt) {
        const int cur = (kt - kt0) & 1;
        if (kt + 1 < ktEnd) {
            const int j1 = (kt + 1) * 64;
            gload16(Kg + (size_t)(j1 + srow) * 64 + ((sch ^ (srow & 7)) << 3),
                    Ks[cur ^ 1] + srow * 64 + (sch << 3));
            gload16(Kg + (size_t)(j1 + srow2) * 64 + ((sch2 ^ (srow2 & 7)) << 3),
                    Ks[cur ^ 1] + srow2 * 64 + (sch2 << 3));
            gload16(Vg + (size_t)srow * L_DIM + j1 + ((sch ^ (srow & 7)) << 3),
                    Vs[cur ^ 1] + srow * 64 + (sch << 3));
            gload16(Vg + (size_t)srow2 * L_DIM + j1 + ((sch2 ^ (srow2 & 7)) << 3),
                    Vs[cur ^ 1] + srow2 * 64 + (sch2 << 3));
        }
        const int j0 = kt * 64;

        // ---- S^T = K . Q^T ----
        bf16x8 ak[4][2];
        #pragma unroll
        for (int kt4 = 0; kt4 < 4; ++kt4)
            #pragma unroll
            for (int kc = 0; kc < 2; ++kc) {
                const int row = 16 * kt4 + l15;
                ak[kt4][kc] = *(const bf16x8*)&Ks[cur][row * 64 + (((4 * kc + g) ^ (row & 7)) << 3)];
            }
        f32x4 st[4];
        #pragma unroll
        for (int kt4 = 0; kt4 < 4; ++kt4) st[kt4] = f32x4{0.f, 0.f, 0.f, 0.f};
        __builtin_amdgcn_s_setprio(1);
        #pragma unroll
        for (int kc = 0; kc < 2; ++kc)
            #pragma unroll
            for (int kt4 = 0; kt4 < 4; ++kt4)
                st[kt4] = __builtin_amdgcn_mfma_f32_16x16x32_bf16(
                    ak[kt4][kc], qf[kc], st[kt4], 0, 0, 0);
        __builtin_amdgcn_s_setprio(0);

        // ---- score -> e (log2 domain, shifted by M); in-lane max ----
        const float negM = -M;
        float emax = -1e30f;
        #pragma unroll
        for (int kt4 = 0; kt4 < 4; ++kt4)
            #pragma unroll
            for (int r = 0; r < 4; ++r) {
                const float x = st[kt4][r];
                const float t = (x * x) * LOG2E;
                const float d = fmaf(-2.f, x, C_CONST);
                float rr;
                asm("v_rcp_f32 %0, %1" : "=v"(rr) : "v"(d));
                const float e = fmaf(t, rr, negM);
                st[kt4][r] = e;
                emax = fmaxf(emax, e);
            }

        if (kt == qt) {   // diagonal tile: mask e, recompute emax
            emax = -1e30f;
            #pragma unroll
            for (int kt4 = 0; kt4 < 4; ++kt4)
                #pragma unroll
                for (int r = 0; r < 4; ++r) {
                    const int key = j0 + 16 * kt4 + 4 * g + r;
                    float e = st[kt4][r];
                    e = (key > qrow) ? -100.f : e;
                    st[kt4][r] = e;
                    emax = fmaxf(emax, e);
                }
        }

        if (__any(emax > 0.f)) {   // rare: score exceeded fixed shift
            float rm = fmaxf(emax, __shfl_xor(emax, 16));
            rm = fmaxf(rm, __shfl_xor(rm, 32));
            rm = fmaxf(rm, 0.f);               // rows not exceeding keep shift
            #pragma unroll
            for (int kt4 = 0; kt4 < 4; ++kt4)
                #pragma unroll
                for (int r = 0; r < 4; ++r) st[kt4][r] -= rm;
            const float nrm = -rm;
            float scl;
            asm("v_exp_f32 %0, %1" : "=v"(scl) : "v"(nrm));
            l_i *= scl;
            #pragma unroll
            for (int r = 0; r < 4; ++r) {
                const float sv = __shfl(scl, 4 * g + r);
                #pragma unroll
                for (int dt = 0; dt < 4; ++dt) o[dt][r] *= sv;
            }
            M += rm;
        }

        // ---- p = exp2(e); per-lane partial sum; pack via cvt_pk ----
        float ts = 0.f;
        #pragma unroll
        for (int kt4 = 0; kt4 < 4; ++kt4) {
            const float e0 = st[kt4][0], e1 = st[kt4][1];
            const float e2 = st[kt4][2], e3 = st[kt4][3];
            float p0, p1, p2, p3;
            asm("v_exp_f32 %0, %1" : "=v"(p0) : "v"(e0));
            asm("v_exp_f32 %0, %1" : "=v"(p1) : "v"(e1));
            asm("v_exp_f32 %0, %1" : "=v"(p2) : "v"(e2));
            asm("v_exp_f32 %0, %1" : "=v"(p3) : "v"(e3));
            ts += (p0 + p1) + (p2 + p3);
            uint2 pk;
            asm("v_cvt_pk_bf16_f32 %0, %1, %2" : "=v"(pk.x) : "v"(p0), "v"(p1));
            asm("v_cvt_pk_bf16_f32 %0, %1, %2" : "=v"(pk.y) : "v"(p2), "v"(p3));
            const int ch = 2 * kt4 + (g >> 1);
            *(uint2*)&Pw[l15 * 64 + ((ch ^ (l15 & 7)) << 3) + 4 * (g & 1)] = pk;
        }
        l_i += ts;

        // ---- O += P . V ----
        bf16x8 ap[2], av[4][2];
        #pragma unroll
        for (int kc = 0; kc < 2; ++kc)
            ap[kc] = *(const bf16x8*)&Pw[l15 * 64 + (((4 * kc + g) ^ (l15 & 7)) << 3)];
        #pragma unroll
        for (int dt = 0; dt < 4; ++dt)
            #pragma unroll
            for (int kc = 0; kc < 2; ++kc) {
                const int row = 16 * dt + l15;
                av[dt][kc] = *(const bf16x8*)&Vs[cur][row * 64 + (((4 * kc + g) ^ (row & 7)) << 3)];
            }
        __builtin_amdgcn_s_setprio(1);
        #pragma unroll
        for (int kc = 0; kc < 2; ++kc)
            #pragma unroll
            for (int dt = 0; dt < 4; ++dt)
                o[dt] = __builtin_amdgcn_mfma_f32_16x16x32_bf16(
                    ap[kc], av[dt][kc], o[dt], 0, 0, 0);
        __builtin_amdgcn_s_setprio(0);

        __syncthreads();   // drains next-tile staging; releases cur buffer
    }

    // ---- epilogue: write partials (no divide); pm in natural-log domain ----
    l_i += __shfl_xor(l_i, 16);
    l_i += __shfl_xor(l_i, 32);
    ushort_t* po = pO + (size_t)cid * 4096 + (16 * w) * 64;
    #pragma unroll
    for (int r = 0; r < 4; ++r)
        #pragma unroll
        for (int dt = 0; dt < 4; ++dt)
            po[(4 * g + r) * 64 + 16 * dt + l15] = (ushort_t)f2bf(o[dt][r]);
    if (lane < 16) {
        pl[cid * 64 + 16 * w + lane] = l_i;
        pm[cid * 64 + 16 * w + lane] = M * LN2;
    }
}

// ---------------------------------------------------------------------------
// combine: merge <=4 chunk partials per (bh, qt); divide; write cb [M][E] bf16
// ---------------------------------------------------------------------------
__global__ __launch_bounds__(256) void combine_kernel(
    const ushort_t* __restrict__ pO, const float* __restrict__ pl,
    const float* __restrict__ pm, ushort_t* __restrict__ cb)
{
    const int qt = blockIdx.x, bh = blockIdx.y;
    const int gg = qt >> 3, ns = gg + 1;
    const int cid0 = bh * NCH_BH + 4 * gg * (gg + 1) + (qt & 7) * (gg + 1);
    const int tid = threadIdx.x;
    const int row = tid >> 2, seg = tid & 3;

    float mt = -1e30f;
    for (int s2 = 0; s2 < ns; ++s2)
        mt = fmaxf(mt, pm[(cid0 + s2) * 64 + row]);

    float acc[16];
    #pragma unroll
    for (int j = 0; j < 16; ++j) acc[j] = 0.f;
    float l_tot = 0.f;
    for (int s2 = 0; s2 < ns; ++s2) {
        const int cid = cid0 + s2;
        const float sc = __expf(pm[cid * 64 + row] - mt);
        l_tot += pl[cid * 64 + row] * sc;
        const ushort_t* src = pO + (size_t)cid * 4096 + row * 64 + seg * 16;
        const uint4 u0 = *(const uint4*)src;
        const uint4 u1 = *(const uint4*)(src + 8);
        const unsigned int uu[8] = {u0.x, u0.y, u0.z, u0.w, u1.x, u1.y, u1.z, u1.w};
        #pragma unroll
        for (int j = 0; j < 8; ++j) {
            acc[2 * j]     = fmaf(sc, bf2f_lo(uu[j]), acc[2 * j]);
            acc[2 * j + 1] = fmaf(sc, bf2f_hi(uu[j]), acc[2 * j + 1]);
        }
    }
    const float inv = 1.0f / l_tot;
    const int b = bh >> 4, h = bh & 15;
    ushort_t* dst = cb + ((size_t)(b * L_DIM + qt * 64 + row)) * E_DIM + h * HD + seg * 16;
    uint4 w0, w1;
    w0.x = f2bf(acc[0] * inv)  | (f2bf(acc[1] * inv) << 16);
    w0.y = f2bf(acc[2] * inv)  | (f2bf(acc[3] * inv) << 16);
    w0.z = f2bf(acc[4] * inv)  | (f2bf(acc[5] * inv) << 16);
    w0.w = f2bf(acc[6] * inv)  | (f2bf(acc[7] * inv) << 16);
    w1.x = f2bf(acc[8] * inv)  | (f2bf(acc[9] * inv) << 16);
    w1.y = f2bf(acc[10] * inv) | (f2bf(acc[11] * inv) << 16);
    w1.z = f2bf(acc[12] * inv) | (f2bf(acc[13] * inv) << 16);
    w1.w = f2bf(acc[14] * inv) | (f2bf(acc[15] * inv) << 16);
    *(uint4*)dst = w0;
    *(uint4*)(dst + 8) = w1;
}

// ---------------------------------------------------------------------------
extern "C" void kernel_launch(void* const* d_in, const int* in_sizes, int n_in,
                              void* d_out, int out_size, void* d_ws, size_t ws_size,
                              hipStream_t stream)
{
    const float* x    = (const float*)d_in[0];
    const float* Wqkv = (const float*)d_in[1];
    const float* bqkv = (const float*)d_in[2];
    const float* Wout = (const float*)d_in[3];
    const float* bout = (const float*)d_in[4];
    float* out = (float*)d_out;

    char* ws = (char*)d_ws;
    const size_t MB = 1u << 20;
    ushort_t* qn16  = (ushort_t*)(ws + 0 * MB);    // [0,8)
    ushort_t* kn16  = (ushort_t*)(ws + 8 * MB);    // [8,16)
    ushort_t* vb16  = (ushort_t*)(ws + 16 * MB);   // [16,24) dead after vt_transpose
    ushort_t* vt16  = (ushort_t*)(ws + 24 * MB);   // [24,32)
    ushort_t* xb    = (ushort_t*)(ws + 32 * MB);   // [32,40) dead after qkv gemm
    ushort_t* cb    = (ushort_t*)(ws + 32 * MB);   // reuse xb slot
    ushort_t* WqkvT = (ushort_t*)(ws + 40 * MB);   // [40,46) dead after qkv gemm
    ushort_t* pO    = (ushort_t*)(ws + 40 * MB);   // [40,60) 2560 x 8KB (reuse WqkvT+)
    float*    pl    = (float*)   (ws + 60 * MB);   // [60,60.66)
    float*    pm    = (float*)   (ws + 61 * MB);   // [61,61.66)
    ushort_t* WoutT = (ushort_t*)(ws + 62 * MB);   // [62,64)

    // 1) bf16 copies for the qkv GEMM
    cast_bf16_kernel<<<4096, 256, 0, stream>>>(x, xb, (M_ROWS * E_DIM) / 4);
    transpose_bf16_kernel<<<dim3(QKV_N / 64, E_DIM / 64), 256, 0, stream>>>(Wqkv, WqkvT, E_DIM, QKV_N);

    // 2) qkv GEMM with fused normalize: qn16, kn16, vb16
    gemm_bt_kernel<QKV_N, 0><<<dim3(M_ROWS / 128, QKV_N / 128), 256, 0, stream>>>(
        xb, WqkvT, bqkv, nullptr, qn16, kn16, vb16);

    // 3) transpose v -> vt16 [bh][d][key]
    vt_transpose_kernel<<<dim3(L_DIM / 64, B_DIM * H_DIM), 256, 0, stream>>>(vb16, vt16);

    // 4) W_out transpose (independent)
    transpose_bf16_kernel<<<dim3(E_DIM / 64, E_DIM / 64), 256, 0, stream>>>(Wout, WoutT, E_DIM, E_DIM);

    // 5) split-K MFMA flash attention -> partials
    attn_mfma_kernel<<<dim3(NCH_BH, B_DIM * H_DIM), 256, 0, stream>>>(qn16, kn16, vt16, pO, pl, pm);

    // 6) combine partials -> cb [M][E] bf16
    combine_kernel<<<dim3(L_DIM / 64, B_DIM * H_DIM), 256, 0, stream>>>(pO, pl, pm, cb);

    // 7) out = ctx @ W_out + b (MFMA)
    gemm_bt_kernel<E_DIM, 1><<<dim3(M_ROWS / 128, E_DIM / 128), 256, 0, stream>>>(
        cb, WoutT, bout, out, nullptr, nullptr, nullptr);
}

// Round 13
// 122.832 us; speedup vs baseline: 2.0252x; 1.0560x over previous
//
#include <hip/hip_runtime.h>
#include <cstdint>
#include <cstddef>

// Problem dims (compile-time)
#define B_DIM 2
#define L_DIM 2048
#define E_DIM 1024
#define H_DIM 16
#define HD    64
#define M_ROWS (B_DIM * L_DIM)   // 4096
#define QKV_N  (3 * E_DIM)       // 3072
#define C_CONST 2.01f
#define NCH_BH 40                // chunks per bh at QBLK=128: sum ceil((2qt'+2)/8)
#define LOG2E 1.4426950408889634f
#define LN2   0.6931471805599453f

typedef unsigned short ushort_t;
typedef __attribute__((ext_vector_type(8))) short bf16x8;
typedef __attribute__((ext_vector_type(4))) float f32x4;

__device__ __forceinline__ unsigned int f2bf(float f) {
    union { float f; unsigned int u; } v; v.f = f;
    return (v.u + 0x7FFFu + ((v.u >> 16) & 1u)) >> 16;   // RNE
}
__device__ __forceinline__ float bf2f_lo(unsigned int u) {
    union { unsigned int u; float f; } v; v.u = u << 16; return v.f;
}
__device__ __forceinline__ float bf2f_hi(unsigned int u) {
    union { unsigned int u; float f; } v; v.u = u & 0xffff0000u; return v.f;
}

__device__ __forceinline__ void gload16(const void* g, void* l) {
    __builtin_amdgcn_global_load_lds(
        (const __attribute__((address_space(1))) void*)g,
        (__attribute__((address_space(3))) void*)l, 16, 0, 0);
}

// ---------------------------------------------------------------------------
// prep: merged cast(x->bf16) + transpose(Wqkv) + transpose(Wout).
// Branch is block-uniform: [0,4096) cast, [4096,4864) Wqkv^T, [4864,5120) Wout^T.
// ---------------------------------------------------------------------------
__device__ __forceinline__ void transpose_tile_dev(
    const float* __restrict__ in, ushort_t* __restrict__ out,
    int R, int Cn, int c0, int r0, int tid, float t[64][65])
{
    for (int idx = tid; idx < 4096; idx += 256) {
        const int r = idx >> 6, c = idx & 63;
        t[r][c] = in[(size_t)(r0 + r) * Cn + c0 + c];
    }
    __syncthreads();
    for (int idx = tid; idx < 4096; idx += 256) {
        const int c = idx >> 6, r = idx & 63;
        out[(size_t)(c0 + c) * R + r0 + r] = (ushort_t)f2bf(t[r][c]);
    }
}

__global__ __launch_bounds__(256) void prep_kernel(
    const float* __restrict__ x, ushort_t* __restrict__ xb,
    const float* __restrict__ Wqkv, ushort_t* __restrict__ WqkvT,
    const float* __restrict__ Wout, ushort_t* __restrict__ WoutT)
{
    __shared__ float t[64][65];
    const int bx = blockIdx.x;
    const int tid = threadIdx.x;
    if (bx < 4096) {
        const int i = bx * 256 + tid;          // exactly 4096*256 = M*E/4 elems
        const float4 v = ((const float4*)x)[i];
        uint2 p;
        p.x = f2bf(v.x) | (f2bf(v.y) << 16);
        p.y = f2bf(v.z) | (f2bf(v.w) << 16);
        ((uint2*)xb)[i] = p;
    } else if (bx < 4096 + 768) {
        const int idx = bx - 4096;             // 48 x 16 tiles
        transpose_tile_dev(Wqkv, WqkvT, E_DIM, QKV_N, (idx % 48) * 64, (idx / 48) * 64, tid, t);
    } else {
        const int idx = bx - 4864;             // 16 x 16 tiles
        transpose_tile_dev(Wout, WoutT, E_DIM, E_DIM, (idx & 15) * 64, (idx >> 4) * 64, tid, t);
    }
}

// ---------------------------------------------------------------------------
// bf16 MFMA GEMM, 128x128 tile, BK=32, 4 waves.
// MODE 0: qkv; fused epilogue: q,k L2-normalized -> bf16 [bh][l][d];
//         v -> bf16 [bh][l][d].  MODE 1: plain C+bias fp32 [M][E].
// ---------------------------------------------------------------------------
template<int NCOLS, int MODE>
__global__ __launch_bounds__(256) void gemm_bt_kernel(
    const ushort_t* __restrict__ A, const ushort_t* __restrict__ BT,
    const float* __restrict__ bias, float* __restrict__ outf,
    ushort_t* __restrict__ q16, ushort_t* __restrict__ k16,
    ushort_t* __restrict__ v16)
{
    __shared__ __align__(16) ushort_t Abuf[128 * 32];
    __shared__ __align__(16) ushort_t Bbuf[128 * 32];
    const int tid = threadIdx.x;
    const int wave = tid >> 6, lane = tid & 63;
    const int m0 = blockIdx.x * 128, n0 = blockIdx.y * 128;
    const int wr = (wave >> 1) * 64, wc = (wave & 1) * 64;
    const int g = lane >> 4, l15 = lane & 15;

    f32x4 acc[4][4];
    #pragma unroll
    for (int i = 0; i < 4; ++i)
        #pragma unroll
        for (int j = 0; j < 4; ++j) acc[i][j] = f32x4{0.f, 0.f, 0.f, 0.f};

    const int sr = tid >> 2;
    const int sc = (tid & 3) * 8;
    const ushort_t* Asrc0 = A + (size_t)(m0 + sr) * 1024 + sc;
    const ushort_t* Asrc1 = A + (size_t)(m0 + 64 + sr) * 1024 + sc;
    const ushort_t* Bsrc0 = BT + (size_t)(n0 + sr) * 1024 + sc;
    const ushort_t* Bsrc1 = BT + (size_t)(n0 + 64 + sr) * 1024 + sc;
    ushort_t* Adst0 = &Abuf[tid * 8];
    ushort_t* Adst1 = &Abuf[2048 + tid * 8];
    ushort_t* Bdst0 = &Bbuf[tid * 8];
    ushort_t* Bdst1 = &Bbuf[2048 + tid * 8];

    for (int k0 = 0; k0 < 1024; k0 += 32) {
        __syncthreads();
        gload16(Asrc0 + k0, Adst0);
        gload16(Asrc1 + k0, Adst1);
        gload16(Bsrc0 + k0, Bdst0);
        gload16(Bsrc1 + k0, Bdst1);
        __syncthreads();

        bf16x8 af[4];
        #pragma unroll
        for (int mt = 0; mt < 4; ++mt)
            af[mt] = *(const bf16x8*)&Abuf[(wr + mt * 16 + l15) * 32 + 8 * g];
        #pragma unroll
        for (int nt = 0; nt < 4; ++nt) {
            const bf16x8 bfr = *(const bf16x8*)&Bbuf[(wc + nt * 16 + l15) * 32 + 8 * g];
            #pragma unroll
            for (int mt = 0; mt < 4; ++mt)
                acc[mt][nt] = __builtin_amdgcn_mfma_f32_16x16x32_bf16(af[mt], bfr, acc[mt][nt], 0, 0, 0);
        }
    }

    if (MODE == 0) {
        const int nBase = n0 + wc;
        const int sel = nBase >> 10;            // 0=q 1=k 2=v
        const int h   = (nBase & 1023) >> 6;
        float bv[4];
        #pragma unroll
        for (int nt = 0; nt < 4; ++nt) bv[nt] = bias[nBase + nt * 16 + l15];

        if (sel <= 1) {
            ushort_t* dst16 = (sel == 0) ? q16 : k16;
            #pragma unroll
            for (int mt = 0; mt < 4; ++mt) {
                float val[4][4], ss[4] = {0.f, 0.f, 0.f, 0.f};
                #pragma unroll
                for (int nt = 0; nt < 4; ++nt)
                    #pragma unroll
                    for (int r = 0; r < 4; ++r) {
                        const float v = acc[mt][nt][r] + bv[nt];
                        val[nt][r] = v;
                        ss[r] = fmaf(v, v, ss[r]);
                    }
                #pragma unroll
                for (int r = 0; r < 4; ++r) {
                    float t = ss[r];
                    t += __shfl_xor(t, 1); t += __shfl_xor(t, 2);
                    t += __shfl_xor(t, 4); t += __shfl_xor(t, 8);
                    ss[r] = 1.0f / sqrtf(t);
                }
                #pragma unroll
                for (int r = 0; r < 4; ++r) {
                    const int m = m0 + wr + mt * 16 + 4 * g + r;
                    const int bb = m >> 11, ll = m & 2047;
                    ushort_t* base = dst16 + ((size_t)((bb * H_DIM + h) * L_DIM + ll)) * HD + l15;
                    #pragma unroll
                    for (int nt = 0; nt < 4; ++nt)
                        base[nt * 16] = (ushort_t)f2bf(val[nt][r] * ss[r]);
                }
            }
        } else {
            #pragma unroll
            for (int mt = 0; mt < 4; ++mt)
                #pragma unroll
                for (int r = 0; r < 4; ++r) {
                    const int m = m0 + wr + mt * 16 + 4 * g + r;
                    const int bb = m >> 11, ll = m & 2047;
                    ushort_t* base = v16 + ((size_t)((bb * H_DIM + h) * L_DIM + ll)) * HD + l15;
                    #pragma unroll
                    for (int nt = 0; nt < 4; ++nt)
                        base[nt * 16] = (ushort_t)f2bf(acc[mt][nt][r] + bv[nt]);
                }
        }
    } else {
        #pragma unroll
        for (int nt = 0; nt < 4; ++nt) {
            const int n = n0 + wc + nt * 16 + l15;
            const float bvv = bias[n];
            #pragma unroll
            for (int mt = 0; mt < 4; ++mt)
                #pragma unroll
                for (int r = 0; r < 4; ++r) {
                    const int m = m0 + wr + mt * 16 + 4 * g + r;
                    outf[(size_t)m * E_DIM + n] = acc[mt][nt][r] + bvv;
                }
        }
    }
}

// ---------------------------------------------------------------------------
// transpose vb16 [bh][key][64] -> vt16 [bh][d][2048]
// ---------------------------------------------------------------------------
__global__ __launch_bounds__(256) void vt_transpose_kernel(
    const ushort_t* __restrict__ vb, ushort_t* __restrict__ vt)
{
    __shared__ ushort_t t[64][68];
    const int kt = blockIdx.x, bh = blockIdx.y;
    const int tid = threadIdx.x;
    const ushort_t* src = vb + ((size_t)bh * L_DIM + kt * 64) * HD;
    #pragma unroll
    for (int p = 0; p < 16; ++p) {
        const int idx = tid + 256 * p;
        t[idx >> 6][idx & 63] = src[idx];
    }
    __syncthreads();
    ushort_t* dst = vt + (size_t)bh * HD * L_DIM + kt * 64;
    #pragma unroll
    for (int p = 0; p < 16; ++p) {
        const int idx = tid + 256 * p;
        const int d = idx >> 6, k = idx & 63;
        dst[(size_t)d * L_DIM + k] = t[k][d];
    }
}

// ---------------------------------------------------------------------------
// Split-K MFMA flash attention, QBLK=128, 8 waves (512 thr), kv tile 64.
// Block = chunk (qt', s): 128 q-rows x <=8 kv tiles. Double-buffered K/V.
// Log2-domain fixed-shift softmax (M = 8*log2e) with guarded rescale
// fallback. Emits partials: pO bf16 [cid][128][64], pl/pm fp32 [cid][128].
// ---------------------------------------------------------------------------
__global__ __launch_bounds__(512) void attn_mfma_kernel(
    const ushort_t* __restrict__ qn, const ushort_t* __restrict__ kn,
    const ushort_t* __restrict__ vt,
    ushort_t* __restrict__ pO, float* __restrict__ pl, float* __restrict__ pm)
{
    __shared__ __align__(16) ushort_t Qs[128 * 64];     // Q; reused as P
    __shared__ __align__(16) ushort_t Ks[2][64 * 64];
    __shared__ __align__(16) ushort_t Vs[2][64 * 64];

    // decode chunk id -> (qt', s);  group gg: qt' in [4gg,4gg+3], gg+1 chunks
    int c = blockIdx.x, qtp = 0, s = 0;
    #pragma unroll
    for (int gg = 0; gg < 4; ++gg) {
        const int sz = 4 * (gg + 1);
        if (c < sz) { qtp = 4 * gg + c / (gg + 1); s = c - (c / (gg + 1)) * (gg + 1); break; }
        c -= sz;
    }
    const int bh = blockIdx.y;
    const int cid = bh * NCH_BH + blockIdx.x;
    const int q0 = qtp * 128;
    const int kt0 = 8 * s;
    const int ktEnd = min(8 * s + 8, 2 * qtp + 2);

    const int tid = threadIdx.x, w = tid >> 6, lane = tid & 63;
    const int g = lane >> 4, l15 = lane & 15;
    ushort_t* Pw = &Qs[w * 16 * 64];                // wave's own dead Q rows

    const ushort_t* Qg = qn + ((size_t)bh * L_DIM + q0) * HD;
    const ushort_t* Kg = kn + (size_t)bh * L_DIM * HD;
    const ushort_t* Vg = vt + (size_t)bh * HD * L_DIM;

    const int srow = tid >> 3, sch = tid & 7;               // rows 0..63
    const int qr2 = (tid + 512) >> 3, qc2 = (tid + 512) & 7; // Q rows 64..127

    // prologue: stage Q (2 chunks/thr) + K/V tile kt0 (1 chunk/thr each)
    {
        const int j0 = kt0 * 64;
        gload16(Qg + srow * 64 + ((sch ^ (srow & 7)) << 3), Qs + srow * 64 + (sch << 3));
        gload16(Qg + qr2 * 64 + ((qc2 ^ (qr2 & 7)) << 3), Qs + qr2 * 64 + (qc2 << 3));
        gload16(Kg + (size_t)(j0 + srow) * 64 + ((sch ^ (srow & 7)) << 3), Ks[0] + srow * 64 + (sch << 3));
        gload16(Vg + (size_t)srow * L_DIM + j0 + ((sch ^ (srow & 7)) << 3), Vs[0] + srow * 64 + (sch << 3));
    }
    __syncthreads();

    bf16x8 qf[2];
    #pragma unroll
    for (int kc = 0; kc < 2; ++kc) {
        const int row = 16 * w + l15;
        qf[kc] = *(const bf16x8*)&Qs[row * 64 + (((4 * kc + g) ^ (row & 7)) << 3)];
    }

    f32x4 o[4];
    float M = 8.0f * LOG2E, l_i = 0.f;   // shift in log2 domain
    #pragma unroll
    for (int j = 0; j < 4; ++j) o[j] = f32x4{0.f, 0.f, 0.f, 0.f};

    const int qrow = q0 + 16 * w + l15;

    for (int kt = kt0; kt < ktEnd; ++kt) {
        const int cur = (kt - kt0) & 1;
        if (kt + 1 < ktEnd) {
            const int j1 = (kt + 1) * 64;
            gload16(Kg + (size_t)(j1 + srow) * 64 + ((sch ^ (srow & 7)) << 3),
                    Ks[cur ^ 1] + srow * 64 + (sch << 3));
            gload16(Vg + (size_t)srow * L_DIM + j1 + ((sch ^ (srow & 7)) << 3),
                    Vs[cur ^ 1] + srow * 64 + (sch << 3));
        }
        const int j0 = kt * 64;

        // ---- S^T = K . Q^T ----
        bf16x8 ak[4][2];
        #pragma unroll
        for (int kt4 = 0; kt4 < 4; ++kt4)
            #pragma unroll
            for (int kc = 0; kc < 2; ++kc) {
                const int row = 16 * kt4 + l15;
                ak[kt4][kc] = *(const bf16x8*)&Ks[cur][row * 64 + (((4 * kc + g) ^ (row & 7)) << 3)];
            }
        f32x4 st[4];
        #pragma unroll
        for (int kt4 = 0; kt4 < 4; ++kt4) st[kt4] = f32x4{0.f, 0.f, 0.f, 0.f};
        __builtin_amdgcn_s_setprio(1);
        #pragma unroll
        for (int kc = 0; kc < 2; ++kc)
            #pragma unroll
            for (int kt4 = 0; kt4 < 4; ++kt4)
                st[kt4] = __builtin_amdgcn_mfma_f32_16x16x32_bf16(
                    ak[kt4][kc], qf[kc], st[kt4], 0, 0, 0);
        __builtin_amdgcn_s_setprio(0);

        // ---- score -> e (log2 domain, shifted by M); in-lane max ----
        const float negM = -M;
        float emax = -1e30f;
        #pragma unroll
        for (int kt4 = 0; kt4 < 4; ++kt4)
            #pragma unroll
            for (int r = 0; r < 4; ++r) {
                const float x = st[kt4][r];
                const float t = (x * x) * LOG2E;
                const float d = fmaf(-2.f, x, C_CONST);
                float rr;
                asm("v_rcp_f32 %0, %1" : "=v"(rr) : "v"(d));
                const float e = fmaf(t, rr, negM);
                st[kt4][r] = e;
                emax = fmaxf(emax, e);
            }

        if (kt >= 2 * qtp) {   // diagonal region (last two tiles): mask, redo emax
            emax = -1e30f;
            #pragma unroll
            for (int kt4 = 0; kt4 < 4; ++kt4)
                #pragma unroll
                for (int r = 0; r < 4; ++r) {
                    const int key = j0 + 16 * kt4 + 4 * g + r;
                    float e = st[kt4][r];
                    e = (key > qrow) ? -100.f : e;
                    st[kt4][r] = e;
                    emax = fmaxf(emax, e);
                }
        }

        if (__any(emax > 0.f)) {   // score exceeded fixed shift (diag self-score)
            float rm = fmaxf(emax, __shfl_xor(emax, 16));
            rm = fmaxf(rm, __shfl_xor(rm, 32));
            rm = fmaxf(rm, 0.f);               // rows not exceeding keep shift
            #pragma unroll
            for (int kt4 = 0; kt4 < 4; ++kt4)
                #pragma unroll
                for (int r = 0; r < 4; ++r) st[kt4][r] -= rm;
            const float nrm = -rm;
            float scl;
            asm("v_exp_f32 %0, %1" : "=v"(scl) : "v"(nrm));
            l_i *= scl;
            #pragma unroll
            for (int r = 0; r < 4; ++r) {
                const float sv = __shfl(scl, 4 * g + r);
                #pragma unroll
                for (int dt = 0; dt < 4; ++dt) o[dt][r] *= sv;
            }
            M += rm;
        }

        // ---- p = exp2(e); per-lane partial sum; pack via cvt_pk ----
        float ts = 0.f;
        #pragma unroll
        for (int kt4 = 0; kt4 < 4; ++kt4) {
            const float e0 = st[kt4][0], e1 = st[kt4][1];
            const float e2 = st[kt4][2], e3 = st[kt4][3];
            float p0, p1, p2, p3;
            asm("v_exp_f32 %0, %1" : "=v"(p0) : "v"(e0));
            asm("v_exp_f32 %0, %1" : "=v"(p1) : "v"(e1));
            asm("v_exp_f32 %0, %1" : "=v"(p2) : "v"(e2));
            asm("v_exp_f32 %0, %1" : "=v"(p3) : "v"(e3));
            ts += (p0 + p1) + (p2 + p3);
            uint2 pk;
            asm("v_cvt_pk_bf16_f32 %0, %1, %2" : "=v"(pk.x) : "v"(p0), "v"(p1));
            asm("v_cvt_pk_bf16_f32 %0, %1, %2" : "=v"(pk.y) : "v"(p2), "v"(p3));
            const int ch = 2 * kt4 + (g >> 1);
            *(uint2*)&Pw[l15 * 64 + ((ch ^ (l15 & 7)) << 3) + 4 * (g & 1)] = pk;
        }
        l_i += ts;

        // ---- O += P . V ----
        bf16x8 ap[2], av[4][2];
        #pragma unroll
        for (int kc = 0; kc < 2; ++kc)
            ap[kc] = *(const bf16x8*)&Pw[l15 * 64 + (((4 * kc + g) ^ (l15 & 7)) << 3)];
        #pragma unroll
        for (int dt = 0; dt < 4; ++dt)
            #pragma unroll
            for (int kc = 0; kc < 2; ++kc) {
                const int row = 16 * dt + l15;
                av[dt][kc] = *(const bf16x8*)&Vs[cur][row * 64 + (((4 * kc + g) ^ (row & 7)) << 3)];
            }
        __builtin_amdgcn_s_setprio(1);
        #pragma unroll
        for (int kc = 0; kc < 2; ++kc)
            #pragma unroll
            for (int dt = 0; dt < 4; ++dt)
                o[dt] = __builtin_amdgcn_mfma_f32_16x16x32_bf16(
                    ap[kc], av[dt][kc], o[dt], 0, 0, 0);
        __builtin_amdgcn_s_setprio(0);

        __syncthreads();   // drains next-tile staging; releases cur buffer
    }

    // ---- epilogue: write partials (no divide); pm in natural-log domain ----
    l_i += __shfl_xor(l_i, 16);
    l_i += __shfl_xor(l_i, 32);
    ushort_t* po = pO + (size_t)cid * 8192 + (16 * w) * 64;
    #pragma unroll
    for (int r = 0; r < 4; ++r)
        #pragma unroll
        for (int dt = 0; dt < 4; ++dt)
            po[(4 * g + r) * 64 + 16 * dt + l15] = (ushort_t)f2bf(o[dt][r]);
    if (lane < 16) {
        pl[cid * 128 + 16 * w + lane] = l_i;
        pm[cid * 128 + 16 * w + lane] = M * LN2;
    }
}

// ---------------------------------------------------------------------------
// combine: merge <=4 chunk partials per 64-row output tile; write cb bf16
// ---------------------------------------------------------------------------
__global__ __launch_bounds__(256) void combine_kernel(
    const ushort_t* __restrict__ pO, const float* __restrict__ pl,
    const float* __restrict__ pm, ushort_t* __restrict__ cb)
{
    const int qt2 = blockIdx.x, bh = blockIdx.y;     // qt2: 64-row tile 0..31
    const int qtp = qt2 >> 1, half = qt2 & 1;
    const int gg = qtp >> 2, ns = gg + 1;
    const int cid0 = bh * NCH_BH + 2 * gg * (gg + 1) + (qtp & 3) * ns;
    const int tid = threadIdx.x;
    const int row = tid >> 2, seg = tid & 3;
    const int rowc = half * 64 + row;                // row within chunk partial

    float mt = -1e30f;
    for (int s2 = 0; s2 < ns; ++s2)
        mt = fmaxf(mt, pm[(cid0 + s2) * 128 + rowc]);

    float acc[16];
    #pragma unroll
    for (int j = 0; j < 16; ++j) acc[j] = 0.f;
    float l_tot = 0.f;
    for (int s2 = 0; s2 < ns; ++s2) {
        const int cid = cid0 + s2;
        const float sc = __expf(pm[cid * 128 + rowc] - mt);
        l_tot += pl[cid * 128 + rowc] * sc;
        const ushort_t* src = pO + (size_t)cid * 8192 + rowc * 64 + seg * 16;
        const uint4 u0 = *(const uint4*)src;
        const uint4 u1 = *(const uint4*)(src + 8);
        const unsigned int uu[8] = {u0.x, u0.y, u0.z, u0.w, u1.x, u1.y, u1.z, u1.w};
        #pragma unroll
        for (int j = 0; j < 8; ++j) {
            acc[2 * j]     = fmaf(sc, bf2f_lo(uu[j]), acc[2 * j]);
            acc[2 * j + 1] = fmaf(sc, bf2f_hi(uu[j]), acc[2 * j + 1]);
        }
    }
    const float inv = 1.0f / l_tot;
    const int b = bh >> 4, h = bh & 15;
    ushort_t* dst = cb + ((size_t)(b * L_DIM + qt2 * 64 + row)) * E_DIM + h * HD + seg * 16;
    uint4 w0, w1;
    w0.x = f2bf(acc[0] * inv)  | (f2bf(acc[1] * inv) << 16);
    w0.y = f2bf(acc[2] * inv)  | (f2bf(acc[3] * inv) << 16);
    w0.z = f2bf(acc[4] * inv)  | (f2bf(acc[5] * inv) << 16);
    w0.w = f2bf(acc[6] * inv)  | (f2bf(acc[7] * inv) << 16);
    w1.x = f2bf(acc[8] * inv)  | (f2bf(acc[9] * inv) << 16);
    w1.y = f2bf(acc[10] * inv) | (f2bf(acc[11] * inv) << 16);
    w1.z = f2bf(acc[12] * inv) | (f2bf(acc[13] * inv) << 16);
    w1.w = f2bf(acc[14] * inv) | (f2bf(acc[15] * inv) << 16);
    *(uint4*)dst = w0;
    *(uint4*)(dst + 8) = w1;
}

// ---------------------------------------------------------------------------
extern "C" void kernel_launch(void* const* d_in, const int* in_sizes, int n_in,
                              void* d_out, int out_size, void* d_ws, size_t ws_size,
                              hipStream_t stream)
{
    const float* x    = (const float*)d_in[0];
    const float* Wqkv = (const float*)d_in[1];
    const float* bqkv = (const float*)d_in[2];
    const float* Wout = (const float*)d_in[3];
    const float* bout = (const float*)d_in[4];
    float* out = (float*)d_out;

    char* ws = (char*)d_ws;
    const size_t MB = 1u << 20;
    ushort_t* qn16  = (ushort_t*)(ws + 0 * MB);    // [0,8)
    ushort_t* kn16  = (ushort_t*)(ws + 8 * MB);    // [8,16)
    ushort_t* vb16  = (ushort_t*)(ws + 16 * MB);   // [16,24) dead after vt_transpose
    ushort_t* vt16  = (ushort_t*)(ws + 24 * MB);   // [24,32)
    ushort_t* xb    = (ushort_t*)(ws + 32 * MB);   // [32,40) dead after qkv gemm
    ushort_t* cb    = (ushort_t*)(ws + 32 * MB);   // reuse xb slot
    ushort_t* WqkvT = (ushort_t*)(ws + 40 * MB);   // [40,46) dead after qkv gemm
    ushort_t* pO    = (ushort_t*)(ws + 40 * MB);   // [40,60) 1280 x 16KB = 20 MB
    float*    pl    = (float*)   (ws + 60 * MB);   // [60,60.625)
    float*    pm    = (float*)   (ws + 61 * MB);   // [61,61.625)
    ushort_t* WoutT = (ushort_t*)(ws + 62 * MB);   // [62,64)

    // 1) merged prep: cast x + transpose Wqkv + transpose Wout
    prep_kernel<<<5120, 256, 0, stream>>>(x, xb, Wqkv, WqkvT, Wout, WoutT);

    // 2) qkv GEMM with fused normalize: qn16, kn16, vb16
    gemm_bt_kernel<QKV_N, 0><<<dim3(M_ROWS / 128, QKV_N / 128), 256, 0, stream>>>(
        xb, WqkvT, bqkv, nullptr, qn16, kn16, vb16);

    // 3) transpose v -> vt16 [bh][d][key]
    vt_transpose_kernel<<<dim3(L_DIM / 64, B_DIM * H_DIM), 256, 0, stream>>>(vb16, vt16);

    // 4) split-K MFMA flash attention (QBLK=128, 8 waves) -> partials
    attn_mfma_kernel<<<dim3(NCH_BH, B_DIM * H_DIM), 512, 0, stream>>>(qn16, kn16, vt16, pO, pl, pm);

    // 5) combine partials -> cb [M][E] bf16
    combine_kernel<<<dim3(L_DIM / 64, B_DIM * H_DIM), 256, 0, stream>>>(pO, pl, pm, cb);

    // 6) out = ctx @ W_out + b (MFMA)
    gemm_bt_kernel<E_DIM, 1><<<dim3(M_ROWS / 128, E_DIM / 128), 256, 0, stream>>>(
        cb, WoutT, bout, out, nullptr, nullptr, nullptr);
}